// Round 2
// baseline (5336.374 us; speedup 1.0000x reference)
//
#include <hip/hip_runtime.h>
#include <hip/hip_bf16.h>

// ---------------------------------------------------------------------------
// MGCNN: x_{t+1} = x_t + tanh(c W_out + b_out), LSTM-style gates driven by a
// 2-D Chebyshev graph conv. M=N=768, Q=32, orders 4x4, 3 iterations, fp32.
//
// Decomposition:
//   TrH (768 x 3840): Tr_i stacked horizontally (col block i), same TcH.
//   XRT = x^T @ TrH  (valid because T_k symmetric)  -> XRT[k][i*768+m]
//   conv kernel: acc_ij[m][n] = sum_k XRT[k][i*768+m] * TcH[k][j*768+n]
//                xc[p][o] = sum_ij acc_ij * theta[i][j][o] + bias[o]
//   gate kernel: [xc|h](128x64) @ [W;U](64x128) + LSTM elementwise + x += dx
// ---------------------------------------------------------------------------

#define DIM 768
#define LDT 3840   // 5*768

__device__ __forceinline__ float sigm(float v) {
    return 1.0f / (1.0f + __expf(-v));
}

// ---------------------------------------------------------------------------
// init: TrH block0 = I, block1 = L_row; same for TcH / L_col
// ---------------------------------------------------------------------------
__global__ __launch_bounds__(256) void init_cheb(
    const float* __restrict__ Lrow, const float* __restrict__ Lcol,
    float* __restrict__ TrH, float* __restrict__ TcH)
{
    int idx = blockIdx.x * 256 + threadIdx.x;      // 0 .. 768*768-1
    int p = idx / DIM, m = idx % DIM;
    float eye = (p == m) ? 1.0f : 0.0f;
    TrH[(size_t)p * LDT + m] = eye;
    TrH[(size_t)p * LDT + DIM + m] = Lrow[idx];
    TcH[(size_t)p * LDT + m] = eye;
    TcH[(size_t)p * LDT + DIM + m] = Lcol[idx];
}

// ---------------------------------------------------------------------------
// Dual-batch fp32 GEMM: D = alpha*A@B + beta*C  (64x64 tile, BK=16, 4x4/thr)
// blockIdx.z selects pointer set (used to run the Tr and Tc Cheb steps
// in one launch for better CU utilization).
// ---------------------------------------------------------------------------
__global__ __launch_bounds__(256) void gemm2_f32(
    const float* __restrict__ A0, const float* __restrict__ B0,
    const float* __restrict__ C0, float* __restrict__ D0,
    const float* __restrict__ A1, const float* __restrict__ B1,
    const float* __restrict__ C1, float* __restrict__ D1,
    int lda, int ldb, int ldc, int ldd, int K, float alpha, float beta)
{
    const float* A = blockIdx.z ? A1 : A0;
    const float* B = blockIdx.z ? B1 : B0;
    const float* C = blockIdx.z ? C1 : C0;
    float*       D = blockIdx.z ? D1 : D0;

    __shared__ float As[16][68];   // [k][m], pad to 68 (16B-aligned rows)
    __shared__ float Bs[16][64];   // [k][n]

    const int tid = threadIdx.x;
    const int tx = tid & 15, ty = tid >> 4;
    const int m0 = blockIdx.y * 64, n0 = blockIdx.x * 64;
    const int lr = tid >> 2, lc = tid & 3;    // A-load row / f4 col
    const int br = tid >> 4, bc = tid & 15;   // B-load row / f4 col

    float acc[4][4];
#pragma unroll
    for (int i = 0; i < 4; ++i)
#pragma unroll
        for (int j = 0; j < 4; ++j) acc[i][j] = 0.0f;

    for (int kb = 0; kb < K; kb += 16) {
        float4 av = *(const float4*)&A[(size_t)(m0 + lr) * lda + kb + 4 * lc];
        float4 bv = *(const float4*)&B[(size_t)(kb + br) * ldb + n0 + 4 * bc];
        __syncthreads();
        As[4 * lc + 0][lr] = av.x; As[4 * lc + 1][lr] = av.y;
        As[4 * lc + 2][lr] = av.z; As[4 * lc + 3][lr] = av.w;
        *(float4*)&Bs[br][4 * bc] = bv;
        __syncthreads();
#pragma unroll
        for (int k = 0; k < 16; ++k) {
            float4 a4 = *(const float4*)&As[k][4 * ty];
            float4 b4 = *(const float4*)&Bs[k][4 * tx];
            float a[4] = {a4.x, a4.y, a4.z, a4.w};
            float b[4] = {b4.x, b4.y, b4.z, b4.w};
#pragma unroll
            for (int i = 0; i < 4; ++i)
#pragma unroll
                for (int j = 0; j < 4; ++j)
                    acc[i][j] = fmaf(a[i], b[j], acc[i][j]);
        }
    }
#pragma unroll
    for (int i = 0; i < 4; ++i) {
        size_t row = (size_t)(m0 + 4 * ty + i);
        float4 cv;
        cv.x = alpha * acc[i][0]; cv.y = alpha * acc[i][1];
        cv.z = alpha * acc[i][2]; cv.w = alpha * acc[i][3];
        if (beta != 0.0f) {
            float4 pv = *(const float4*)&C[row * ldc + n0 + 4 * tx];
            cv.x = fmaf(beta, pv.x, cv.x); cv.y = fmaf(beta, pv.y, cv.y);
            cv.z = fmaf(beta, pv.z, cv.z); cv.w = fmaf(beta, pv.w, cv.w);
        }
        *(float4*)&D[row * ldd + n0 + 4 * tx] = cv;
    }
}

// ---------------------------------------------------------------------------
// 768x768 transpose (32x32 LDS tiles)
// ---------------------------------------------------------------------------
__global__ __launch_bounds__(256) void transpose768(
    const float* __restrict__ in, float* __restrict__ out)
{
    __shared__ float t[32][33];
    int x = threadIdx.x & 31, y = threadIdx.x >> 5;   // y: 0..7
    int bx = blockIdx.x * 32, by = blockIdx.y * 32;
#pragma unroll
    for (int r = 0; r < 4; ++r)
        t[y + 8 * r][x] = in[(size_t)(by + y + 8 * r) * DIM + bx + x];
    __syncthreads();
#pragma unroll
    for (int r = 0; r < 4; ++r)
        out[(size_t)(bx + y + 8 * r) * DIM + by + x] = t[x][y + 8 * r];
}

// ---------------------------------------------------------------------------
// Fused conv: 32x32 pixel tile per block, 25 (i,j) products, theta epilogue.
// As[kk][i][m] <- XRT[kb+kk][i*768+tile_m+m];  Bs[kk][j][n] <- TcH[...]
// ---------------------------------------------------------------------------
__global__ __launch_bounds__(256, 3) void conv_theta_kernel(
    const float* __restrict__ XRT, const float* __restrict__ TcH,
    const float* __restrict__ theta, const float* __restrict__ bias,
    float* __restrict__ xc)
{
    __shared__ float As[32 * 5 * 32];
    __shared__ float Bs[32 * 5 * 32];
    __shared__ float sth[800];
    __shared__ float sbias[32];

    const int tid = threadIdx.x;
    const int tx = tid & 15, ty = tid >> 4;
    const int tile_m = blockIdx.y * 32, tile_n = blockIdx.x * 32;

    for (int t = tid; t < 800; t += 256) sth[t] = theta[t];
    if (tid < 32) sbias[tid] = bias[tid];

    float acc[25][2][2];
#pragma unroll
    for (int ij = 0; ij < 25; ++ij) {
        acc[ij][0][0] = 0.f; acc[ij][0][1] = 0.f;
        acc[ij][1][0] = 0.f; acc[ij][1][1] = 0.f;
    }

    for (int kb = 0; kb < DIM; kb += 32) {
        __syncthreads();
#pragma unroll
        for (int cc = 0; cc < 5; ++cc) {
            int idx = cc * 256 + tid;            // 0..1279
            int kk = idx / 40, rest = idx % 40;
            int i = rest >> 3, f = rest & 7;
            *(float4*)&As[(kk * 5 + i) * 32 + 4 * f] =
                *(const float4*)&XRT[(size_t)(kb + kk) * LDT + i * DIM + tile_m + 4 * f];
            *(float4*)&Bs[(kk * 5 + i) * 32 + 4 * f] =
                *(const float4*)&TcH[(size_t)(kb + kk) * LDT + i * DIM + tile_n + 4 * f];
        }
        __syncthreads();
#pragma unroll 4
        for (int kk = 0; kk < 32; ++kk) {
            float2 a[5], b[5];
#pragma unroll
            for (int i = 0; i < 5; ++i) {
                a[i] = *(const float2*)&As[(kk * 5 + i) * 32 + 2 * ty];
                b[i] = *(const float2*)&Bs[(kk * 5 + i) * 32 + 2 * tx];
            }
#pragma unroll
            for (int i = 0; i < 5; ++i)
#pragma unroll
                for (int j = 0; j < 5; ++j) {
                    acc[i * 5 + j][0][0] = fmaf(a[i].x, b[j].x, acc[i * 5 + j][0][0]);
                    acc[i * 5 + j][0][1] = fmaf(a[i].x, b[j].y, acc[i * 5 + j][0][1]);
                    acc[i * 5 + j][1][0] = fmaf(a[i].y, b[j].x, acc[i * 5 + j][1][0]);
                    acc[i * 5 + j][1][1] = fmaf(a[i].y, b[j].y, acc[i * 5 + j][1][1]);
                }
        }
    }

    // theta contraction epilogue -> xc[p][0..31]
    const float4* th4 = (const float4*)sth;
    const float4* b4 = (const float4*)sbias;
#pragma unroll
    for (int dy = 0; dy < 2; ++dy)
#pragma unroll
        for (int dx = 0; dx < 2; ++dx) {
            float4 v[8];
#pragma unroll
            for (int oq = 0; oq < 8; ++oq) v[oq] = b4[oq];
#pragma unroll
            for (int ij = 0; ij < 25; ++ij) {
                float av = acc[ij][dy][dx];
#pragma unroll
                for (int oq = 0; oq < 8; ++oq) {
                    float4 t = th4[ij * 8 + oq];
                    v[oq].x = fmaf(av, t.x, v[oq].x);
                    v[oq].y = fmaf(av, t.y, v[oq].y);
                    v[oq].z = fmaf(av, t.z, v[oq].z);
                    v[oq].w = fmaf(av, t.w, v[oq].w);
                }
            }
            int p = (tile_m + 2 * ty + dy) * DIM + tile_n + 2 * tx + dx;
            float4* out4 = (float4*)&xc[(size_t)p * 32];
#pragma unroll
            for (int oq = 0; oq < 8; ++oq) out4[oq] = v[oq];
        }
}

// ---------------------------------------------------------------------------
// Gate kernel: per block 128 pixels. GEMM [xc|h](128x64) @ [W;U](64x128),
// then sigmoid gates, c/h update, dx = tanh(c . Wout + bout), x += dx.
// Thread (tm,tn): 8 pixels (tm*8..), o-channels {2tn, 2tn+1} for all 4 gates.
// ---------------------------------------------------------------------------
__global__ __launch_bounds__(256) void gate_kernel(
    const float* __restrict__ xc,
    const float* __restrict__ Wf, const float* __restrict__ Wi,
    const float* __restrict__ Wo, const float* __restrict__ Wc,
    const float* __restrict__ Uf, const float* __restrict__ Ui,
    const float* __restrict__ Uo, const float* __restrict__ Uc,
    const float* __restrict__ bfv, const float* __restrict__ biv,
    const float* __restrict__ bov, const float* __restrict__ bcv,
    const float* __restrict__ Wout, const float* __restrict__ bout,
    float* __restrict__ h, float* __restrict__ c, float* __restrict__ x)
{
    __shared__ float As[128 * 68];   // [px][k], k<32: xc, k>=32: h
    __shared__ float Bs[64 * 132];   // [k][g*32+o]

    const int tid = threadIdx.x;
    const int tn = tid & 15, tm = tid >> 4;
    const int pbase = blockIdx.x * 128;

    const float4* xc4 = (const float4*)xc;
    const float4* h4g = (const float4*)h;
    // 128 px * 16 float4 = 2048 f4 writes -> 8 iterations of 256 threads.
    // (16 iters here was an LDS overflow into Bs -> race -> tripwire fail)
#pragma unroll
    for (int cc = 0; cc < 8; ++cc) {
        int idx = cc * 256 + tid;          // 0..2047
        int px = idx >> 4, f = idx & 15;   // px 0..127, k0 = 4*f
        float4 v = (f < 8) ? xc4[(size_t)(pbase + px) * 8 + f]
                           : h4g[(size_t)(pbase + px) * 8 + (f - 8)];
        *(float4*)&As[px * 68 + 4 * f] = v;
    }
    const float* WU[8] = {Wf, Wi, Wo, Wc, Uf, Ui, Uo, Uc};
#pragma unroll
    for (int cc = 0; cc < 8; ++cc) {
        int t = cc * 256 + tid;            // float4 units, 0..2047
        int kk = t >> 5;                   // 0..63
        int gq = t & 31; int g = gq >> 3, q = gq & 7;
        const float* src = (kk < 32) ? WU[g] : WU[4 + g];
        float4 v = *(const float4*)&src[(kk & 31) * 32 + 4 * q];
        *(float4*)&Bs[kk * 132 + g * 32 + 4 * q] = v;
    }
    __syncthreads();

    const int px0 = tm * 8;
    float acc[8][4][2];
#pragma unroll
    for (int i = 0; i < 8; ++i)
#pragma unroll
        for (int g = 0; g < 4; ++g) { acc[i][g][0] = 0.f; acc[i][g][1] = 0.f; }

#pragma unroll 4
    for (int k = 0; k < 64; ++k) {
        float a[8]; float2 b[4];
#pragma unroll
        for (int i = 0; i < 8; ++i) a[i] = As[(px0 + i) * 68 + k];
#pragma unroll
        for (int g = 0; g < 4; ++g)
            b[g] = *(const float2*)&Bs[k * 132 + g * 32 + 2 * tn];
#pragma unroll
        for (int i = 0; i < 8; ++i)
#pragma unroll
            for (int g = 0; g < 4; ++g) {
                acc[i][g][0] = fmaf(a[i], b[g].x, acc[i][g][0]);
                acc[i][g][1] = fmaf(a[i], b[g].y, acc[i][g][1]);
            }
    }

    const float2 bgf = ((const float2*)bfv)[tn];
    const float2 bgi = ((const float2*)biv)[tn];
    const float2 bgo = ((const float2*)bov)[tn];
    const float2 bgc = ((const float2*)bcv)[tn];
    const float2 wo2 = ((const float2*)Wout)[tn];
    const float bo0 = bout[0];

#pragma unroll
    for (int i = 0; i < 8; ++i) {
        int p = pbase + px0 + i;
        float fx = sigm(acc[i][0][0] + bgf.x), fy = sigm(acc[i][0][1] + bgf.y);
        float ix = sigm(acc[i][1][0] + bgi.x), iy = sigm(acc[i][1][1] + bgi.y);
        float ox = sigm(acc[i][2][0] + bgo.x), oy = sigm(acc[i][2][1] + bgo.y);
        float gx = sigm(acc[i][3][0] + bgc.x), gy = sigm(acc[i][3][1] + bgc.y);
        float2 cold = *(const float2*)&c[(size_t)p * 32 + 2 * tn];
        float2 cn;
        cn.x = fx * cold.x + ix * gx;
        cn.y = fy * cold.y + iy * gy;
        float2 hn;
        hn.x = ox * sigm(cn.x);
        hn.y = oy * sigm(cn.y);
        *(float2*)&c[(size_t)p * 32 + 2 * tn] = cn;
        *(float2*)&h[(size_t)p * 32 + 2 * tn] = hn;
        float part = cn.x * wo2.x + cn.y * wo2.y;
        part += __shfl_xor(part, 1, 16);
        part += __shfl_xor(part, 2, 16);
        part += __shfl_xor(part, 4, 16);
        part += __shfl_xor(part, 8, 16);
        if (tn == 0) {
            float v = part + bo0;
            v = fminf(fmaxf(v, -15.f), 15.f);     // tanh overflow guard
            float e = __expf(2.f * v);
            x[p] += (e - 1.f) / (e + 1.f);
        }
    }
}

// ---------------------------------------------------------------------------
extern "C" void kernel_launch(void* const* d_in, const int* in_sizes, int n_in,
                              void* d_out, int out_size, void* d_ws, size_t ws_size,
                              hipStream_t stream)
{
    const float* x_in  = (const float*)d_in[0];
    const float* Lrow  = (const float*)d_in[1];
    const float* Lcol  = (const float*)d_in[2];
    const float* theta = (const float*)d_in[3];
    const float* bias  = (const float*)d_in[4];
    const float* Wf = (const float*)d_in[5];
    const float* Uf = (const float*)d_in[6];
    const float* bf = (const float*)d_in[7];
    const float* Wi = (const float*)d_in[8];
    const float* Ui = (const float*)d_in[9];
    const float* bi = (const float*)d_in[10];
    const float* Wo = (const float*)d_in[11];
    const float* Uo = (const float*)d_in[12];
    const float* bo = (const float*)d_in[13];
    const float* Wc = (const float*)d_in[14];
    const float* Uc = (const float*)d_in[15];
    const float* bc = (const float*)d_in[16];
    const float* Wout = (const float*)d_in[17];
    const float* bout = (const float*)d_in[18];
    (void)in_sizes; (void)n_in; (void)out_size;

    float* out = (float*)d_out;   // used as the working x buffer

    // workspace layout (floats)
    float* ws  = (float*)d_ws;
    float* TrH = ws;                       // 768*3840 = 2,949,120
    float* TcH = TrH + 2949120;            // 2,949,120
    float* XRT = TcH + 2949120;            // 2,949,120
    float* xT  = XRT + 2949120;            //   589,824
    float* xc  = xT  + 589824;             // 18,874,368
    float* h   = xc  + 18874368;           // 18,874,368
    float* c   = h   + 18874368;           // 18,874,368
    // total = 66,060,288 floats = 264.2 MB
    if (ws_size < (size_t)66060288 * 4) return;

    // x working copy = d_out; h = c = 0
    hipMemcpyAsync(out, x_in, (size_t)DIM * DIM * 4, hipMemcpyDeviceToDevice, stream);
    hipMemsetAsync(h, 0, (size_t)18874368 * 4, stream);
    hipMemsetAsync(c, 0, (size_t)18874368 * 4, stream);

    // Cheb basis: T0 = I, T1 = L, Tk = 2 L T_{k-1} - T_{k-2}  (Tr & Tc batched)
    init_cheb<<<DIM * DIM / 256, 256, 0, stream>>>(Lrow, Lcol, TrH, TcH);
    for (int k = 2; k <= 4; ++k) {
        gemm2_f32<<<dim3(12, 12, 2), 256, 0, stream>>>(
            Lrow, TrH + (k - 1) * DIM, TrH + (k - 2) * DIM, TrH + k * DIM,
            Lcol, TcH + (k - 1) * DIM, TcH + (k - 2) * DIM, TcH + k * DIM,
            DIM, LDT, LDT, LDT, DIM, 2.0f, -1.0f);
    }

    for (int it = 0; it < 3; ++it) {
        // XRT = x^T @ TrH   (768 x 3840), valid since Tr_i symmetric
        transpose768<<<dim3(24, 24), 256, 0, stream>>>(out, xT);
        gemm2_f32<<<dim3(60, 12, 1), 256, 0, stream>>>(
            xT, TrH, XRT, XRT,  xT, TrH, XRT, XRT,
            DIM, LDT, LDT, LDT, DIM, 1.0f, 0.0f);
        // conv + theta -> xc
        conv_theta_kernel<<<dim3(24, 24), 256, 0, stream>>>(XRT, TcH, theta, bias, xc);
        // gates + state update + x += tanh(...)
        gate_kernel<<<4608, 256, 0, stream>>>(
            xc, Wf, Wi, Wo, Wc, Uf, Ui, Uo, Uc,
            bf, bi, bo, bc, Wout, bout, h, c, out);
    }
}

// Round 3
// 2886.818 us; speedup vs baseline: 1.8485x; 1.8485x over previous
//
#include <hip/hip_runtime.h>
#include <hip/hip_bf16.h>

// ---------------------------------------------------------------------------
// MGCNN on MI355X — bf16x3 MFMA formulation.
//
//   TrV/TcV: T_i stacked VERTICALLY, row-major (3840 x 768), k-contiguous.
//   stage1:  XRv[(i,m)][q] = sum_p TrV[(i,m)][p] * xT[q][p]      (MFMA, bf16x3)
//   stage2:  C_big[(i,m)][(j,n)] = sum_q XRv[(i,m)][q]*TcV[(j,n)][q]
//   gate:    theta-contract C_big tile -> xc(LDS) -> LSTM gates -> x += dx
//
// bf16x3: a = a1+a2+a3 (RNE splits); keep 6 products a1b1,a1b2,a2b1,a2b2,
// a1b3,a3b1 -> per-term error ~2^-25 (fp32-grade), 6 MFMAs per K-chunk.
// ---------------------------------------------------------------------------

#define DIM 768
#define MXK 589824        // 768*768
#define STK 2949120       // 5*768*768

typedef short bf16x8 __attribute__((ext_vector_type(8)));
typedef float f32x4 __attribute__((ext_vector_type(4)));

__device__ __forceinline__ float sigm(float v) {
    return 1.0f / (1.0f + __expf(-v));
}
__device__ __forceinline__ unsigned short f2bf(float f) {
    unsigned u = __float_as_uint(f);
    return (unsigned short)((u + 0x7FFF + ((u >> 16) & 1)) >> 16);
}
__device__ __forceinline__ float bf2f(unsigned short b) {
    return __uint_as_float(((unsigned)b) << 16);
}
__device__ __forceinline__ void split3(float f, unsigned short& h1,
                                       unsigned short& h2, unsigned short& h3) {
    h1 = f2bf(f);
    float r = f - bf2f(h1);
    h2 = f2bf(r);
    float r2 = r - bf2f(h2);
    h3 = f2bf(r2);
}

// ---------------------------------------------------------------------------
// init: TrV block0 = I, block1 = L_row (row-major); same TcV / L_col
// ---------------------------------------------------------------------------
__global__ __launch_bounds__(256) void init_cheb_v(
    const float* __restrict__ Lrow, const float* __restrict__ Lcol,
    float* __restrict__ TrV, float* __restrict__ TcV)
{
    int idx = blockIdx.x * 256 + threadIdx.x;      // 0 .. 768*768-1
    int p = idx / DIM, m = idx % DIM;
    float eye = (p == m) ? 1.0f : 0.0f;
    TrV[idx] = eye;
    TrV[MXK + idx] = Lrow[idx];
    TcV[idx] = eye;
    TcV[MXK + idx] = Lcol[idx];
}

// ---------------------------------------------------------------------------
// Dual fp32 GEMM (Cheb recursion): D = alpha*A@B + beta*C, 64x64 tile.
// ---------------------------------------------------------------------------
__global__ __launch_bounds__(256) void gemm2_f32(
    const float* __restrict__ A0, const float* __restrict__ B0,
    const float* __restrict__ C0, float* __restrict__ D0,
    const float* __restrict__ A1, const float* __restrict__ B1,
    const float* __restrict__ C1, float* __restrict__ D1,
    int lda, int ldb, int ldc, int ldd, int K, float alpha, float beta)
{
    const float* A = blockIdx.z ? A1 : A0;
    const float* B = blockIdx.z ? B1 : B0;
    const float* C = blockIdx.z ? C1 : C0;
    float*       D = blockIdx.z ? D1 : D0;

    __shared__ float As[16][68];
    __shared__ float Bs[16][64];

    const int tid = threadIdx.x;
    const int tx = tid & 15, ty = tid >> 4;
    const int m0 = blockIdx.y * 64, n0 = blockIdx.x * 64;
    const int lr = tid >> 2, lc = tid & 3;
    const int br = tid >> 4, bc = tid & 15;

    float acc[4][4];
#pragma unroll
    for (int i = 0; i < 4; ++i)
#pragma unroll
        for (int j = 0; j < 4; ++j) acc[i][j] = 0.0f;

    for (int kb = 0; kb < K; kb += 16) {
        float4 av = *(const float4*)&A[(size_t)(m0 + lr) * lda + kb + 4 * lc];
        float4 bv = *(const float4*)&B[(size_t)(kb + br) * ldb + n0 + 4 * bc];
        __syncthreads();
        As[4 * lc + 0][lr] = av.x; As[4 * lc + 1][lr] = av.y;
        As[4 * lc + 2][lr] = av.z; As[4 * lc + 3][lr] = av.w;
        *(float4*)&Bs[br][4 * bc] = bv;
        __syncthreads();
#pragma unroll
        for (int k = 0; k < 16; ++k) {
            float4 a4 = *(const float4*)&As[k][4 * ty];
            float4 b4 = *(const float4*)&Bs[k][4 * tx];
            float a[4] = {a4.x, a4.y, a4.z, a4.w};
            float b[4] = {b4.x, b4.y, b4.z, b4.w};
#pragma unroll
            for (int i = 0; i < 4; ++i)
#pragma unroll
                for (int j = 0; j < 4; ++j)
                    acc[i][j] = fmaf(a[i], b[j], acc[i][j]);
        }
    }
#pragma unroll
    for (int i = 0; i < 4; ++i) {
        size_t row = (size_t)(m0 + 4 * ty + i);
        float4 cv;
        cv.x = alpha * acc[i][0]; cv.y = alpha * acc[i][1];
        cv.z = alpha * acc[i][2]; cv.w = alpha * acc[i][3];
        if (beta != 0.0f) {
            float4 pv = *(const float4*)&C[row * ldc + n0 + 4 * tx];
            cv.x = fmaf(beta, pv.x, cv.x); cv.y = fmaf(beta, pv.y, cv.y);
            cv.z = fmaf(beta, pv.z, cv.z); cv.w = fmaf(beta, pv.w, cv.w);
        }
        *(float4*)&D[row * ldd + n0 + 4 * tx] = cv;
    }
}

// ---------------------------------------------------------------------------
// fp32 -> 3-level bf16 split (hi, mid, lo), float4-vectorized
// ---------------------------------------------------------------------------
__global__ __launch_bounds__(256) void cvt3(
    const float* __restrict__ in, unsigned short* __restrict__ o1,
    unsigned short* __restrict__ o2, unsigned short* __restrict__ o3, int n4)
{
    int idx = blockIdx.x * 256 + threadIdx.x;
    if (idx >= n4) return;
    float4 v = ((const float4*)in)[idx];
    float f[4] = {v.x, v.y, v.z, v.w};
    unsigned short a[4], b[4], c[4];
#pragma unroll
    for (int k = 0; k < 4; ++k) split3(f[k], a[k], b[k], c[k]);
    uint2 pa, pb, pc;
    pa.x = a[0] | ((unsigned)a[1] << 16); pa.y = a[2] | ((unsigned)a[3] << 16);
    pb.x = b[0] | ((unsigned)b[1] << 16); pb.y = b[2] | ((unsigned)b[3] << 16);
    pc.x = c[0] | ((unsigned)c[1] << 16); pc.y = c[2] | ((unsigned)c[3] << 16);
    *(uint2*)&o1[idx * 4] = pa;
    *(uint2*)&o2[idx * 4] = pb;
    *(uint2*)&o3[idx * 4] = pc;
}

// ---------------------------------------------------------------------------
// transpose 768x768 + bf16x3 split:  xT[q][p] = x[p][q]  (3 short outputs)
// ---------------------------------------------------------------------------
__global__ __launch_bounds__(256) void transpose_cvt3(
    const float* __restrict__ in, unsigned short* __restrict__ o1,
    unsigned short* __restrict__ o2, unsigned short* __restrict__ o3)
{
    __shared__ float t[32][33];
    int x = threadIdx.x & 31, y = threadIdx.x >> 5;   // y: 0..7
    int bx = blockIdx.x * 32, by = blockIdx.y * 32;
#pragma unroll
    for (int r = 0; r < 4; ++r)
        t[y + 8 * r][x] = in[(size_t)(by + y + 8 * r) * DIM + bx + x];
    __syncthreads();
#pragma unroll
    for (int r = 0; r < 4; ++r) {
        float v = t[x][y + 8 * r];
        unsigned short h1, h2, h3;
        split3(v, h1, h2, h3);
        size_t o = (size_t)(bx + y + 8 * r) * DIM + by + x;
        o1[o] = h1; o2[o] = h2; o3[o] = h3;
    }
}

// ---------------------------------------------------------------------------
// bf16x3 MFMA GEMM, B-transposed inputs:
//   C[m][n] = sum_k A[m][k] * BT[n][k],  A: M x K, BT: N x K (both k-contig)
// 128x128 tile, BK=32, 4 waves each 64x64 via 4x4 16x16x32 MFMA frags.
// out_bf=0: fp32 C (ldc);  out_bf=1: bf16x3 epilogue -> Cb1/Cb2/Cb3 (ldc).
// ---------------------------------------------------------------------------
__global__ __launch_bounds__(256) void gemm_bt_x3(
    const unsigned short* __restrict__ A1, const unsigned short* __restrict__ A2,
    const unsigned short* __restrict__ A3,
    const unsigned short* __restrict__ B1, const unsigned short* __restrict__ B2,
    const unsigned short* __restrict__ B3,
    float* __restrict__ C,
    unsigned short* __restrict__ Cb1, unsigned short* __restrict__ Cb2,
    unsigned short* __restrict__ Cb3,
    int K, int ldc, int out_bf)
{
    __shared__ unsigned short sA[3][128 * 32];
    __shared__ unsigned short sB[3][128 * 32];

    const int tid = threadIdx.x;
    const int m0 = blockIdx.y * 128, n0 = blockIdx.x * 128;
    const int lane = tid & 63, w = tid >> 6;
    const int wm = (w & 1) * 64, wn = (w >> 1) * 64;
    const int lm = lane & 15, quad = lane >> 4;

    const unsigned short* Ap[3] = {A1 + (size_t)m0 * K, A2 + (size_t)m0 * K,
                                   A3 + (size_t)m0 * K};
    const unsigned short* Bp[3] = {B1 + (size_t)n0 * K, B2 + (size_t)n0 * K,
                                   B3 + (size_t)n0 * K};

    f32x4 acc[4][4] = {};

    const int sr = tid >> 2;          // staging row 0..63 (and +64)
    const int sk = (tid & 3) * 8;     // staging k-chunk (8 shorts = 16B)

    for (int kb = 0; kb < K; kb += 32) {
        uint4 va[3][2], vb[3][2];
#pragma unroll
        for (int l = 0; l < 3; ++l) {
            va[l][0] = *(const uint4*)&Ap[l][(size_t)sr * K + kb + sk];
            va[l][1] = *(const uint4*)&Ap[l][(size_t)(sr + 64) * K + kb + sk];
            vb[l][0] = *(const uint4*)&Bp[l][(size_t)sr * K + kb + sk];
            vb[l][1] = *(const uint4*)&Bp[l][(size_t)(sr + 64) * K + kb + sk];
        }
        __syncthreads();
#pragma unroll
        for (int l = 0; l < 3; ++l) {
            *(uint4*)&sA[l][sr * 32 + sk] = va[l][0];
            *(uint4*)&sA[l][(sr + 64) * 32 + sk] = va[l][1];
            *(uint4*)&sB[l][sr * 32 + sk] = vb[l][0];
            *(uint4*)&sB[l][(sr + 64) * 32 + sk] = vb[l][1];
        }
        __syncthreads();

        bf16x8 bfr[3][4];
#pragma unroll
        for (int l = 0; l < 3; ++l)
#pragma unroll
            for (int fn = 0; fn < 4; ++fn)
                bfr[l][fn] = *(const bf16x8*)&sB[l][(wn + fn * 16 + lm) * 32 + quad * 8];
#pragma unroll
        for (int fm = 0; fm < 4; ++fm) {
            const int ar = (wm + fm * 16 + lm) * 32 + quad * 8;
            bf16x8 a1 = *(const bf16x8*)&sA[0][ar];
            bf16x8 a2 = *(const bf16x8*)&sA[1][ar];
            bf16x8 a3 = *(const bf16x8*)&sA[2][ar];
#pragma unroll
            for (int fn = 0; fn < 4; ++fn) {
                f32x4 a = acc[fm][fn];
                // smallest-magnitude products first
                a = __builtin_amdgcn_mfma_f32_16x16x32_bf16(a3, bfr[0][fn], a, 0, 0, 0);
                a = __builtin_amdgcn_mfma_f32_16x16x32_bf16(a1, bfr[2][fn], a, 0, 0, 0);
                a = __builtin_amdgcn_mfma_f32_16x16x32_bf16(a2, bfr[1][fn], a, 0, 0, 0);
                a = __builtin_amdgcn_mfma_f32_16x16x32_bf16(a2, bfr[0][fn], a, 0, 0, 0);
                a = __builtin_amdgcn_mfma_f32_16x16x32_bf16(a1, bfr[1][fn], a, 0, 0, 0);
                a = __builtin_amdgcn_mfma_f32_16x16x32_bf16(a1, bfr[0][fn], a, 0, 0, 0);
                acc[fm][fn] = a;
            }
        }
    }

    // epilogue: C/D layout col=lane&15, row=quad*4+reg  [verified m89/m91]
#pragma unroll
    for (int fm = 0; fm < 4; ++fm)
#pragma unroll
        for (int fn = 0; fn < 4; ++fn) {
            f32x4 v = acc[fm][fn];
            int col = n0 + wn + fn * 16 + lm;
#pragma unroll
            for (int r = 0; r < 4; ++r) {
                int row = m0 + wm + fm * 16 + quad * 4 + r;
                if (out_bf) {
                    unsigned short h1, h2, h3;
                    split3(v[r], h1, h2, h3);
                    Cb1[(size_t)row * ldc + col] = h1;
                    Cb2[(size_t)row * ldc + col] = h2;
                    Cb3[(size_t)row * ldc + col] = h3;
                } else {
                    C[(size_t)row * ldc + col] = v[r];
                }
            }
        }
}

// ---------------------------------------------------------------------------
// Gate kernel with fused theta contraction.
// Block = 128 pixels of one row m: m = blk/6, n0 = (blk%6)*128.
//   xc[px][o] = sum_ij C_big[i*768+m][j*768+n0+px] * theta[ij][o] + bias[o]
// then GEMM [xc|h](128x64) @ [W;U](64x128) + LSTM elementwise + x += dx.
// ---------------------------------------------------------------------------
__global__ __launch_bounds__(256) void gate_theta_kernel(
    const float* __restrict__ Cb, const float* __restrict__ theta,
    const float* __restrict__ bias,
    const float* __restrict__ Wf, const float* __restrict__ Wi,
    const float* __restrict__ Wo, const float* __restrict__ Wc,
    const float* __restrict__ Uf, const float* __restrict__ Ui,
    const float* __restrict__ Uo, const float* __restrict__ Uc,
    const float* __restrict__ bfv, const float* __restrict__ biv,
    const float* __restrict__ bov, const float* __restrict__ bcv,
    const float* __restrict__ Wout, const float* __restrict__ bout,
    float* __restrict__ h, float* __restrict__ c, float* __restrict__ x)
{
    __shared__ float As[128 * 68];   // [px][k], k<32: xc, k>=32: h
    __shared__ float Bs[64 * 132];   // [k][g*32+o]
    __shared__ float sth[800];
    __shared__ float sbias[32];

    const int tid = threadIdx.x;
    const int tn = tid & 15, tm = tid >> 4;
    const int m = blockIdx.x / 6;
    const int n0 = (blockIdx.x % 6) * 128;
    const int pbase = m * DIM + n0;

    for (int t = tid; t < 800; t += 256) sth[t] = theta[t];
    if (tid < 32) sbias[tid] = bias[tid];

    // stage h -> As[px][32..63]  (128 px * 8 float4 = 1024)
    const float4* h4g = (const float4*)h;
#pragma unroll
    for (int cc = 0; cc < 4; ++cc) {
        int idx = cc * 256 + tid;          // 0..1023
        int px = idx >> 3, q = idx & 7;
        *(float4*)&As[px * 68 + 32 + 4 * q] = h4g[(size_t)(pbase + px) * 8 + q];
    }
    // stage weights
    const float* WU[8] = {Wf, Wi, Wo, Wc, Uf, Ui, Uo, Uc};
#pragma unroll
    for (int cc = 0; cc < 8; ++cc) {
        int t = cc * 256 + tid;
        int kk = t >> 5;
        int gq = t & 31; int g = gq >> 3, q = gq & 7;
        const float* src = (kk < 32) ? WU[g] : WU[4 + g];
        float4 v = *(const float4*)&src[(kk & 31) * 32 + 4 * q];
        *(float4*)&Bs[kk * 132 + g * 32 + 4 * q] = v;
    }
    __syncthreads();   // sth/sbias ready

    // theta contraction: thread covers (px = tid&127, o-half = (tid>>7)*16)
    {
        int px = tid & 127;
        int oh = (tid >> 7) * 16;
        const float* crow = Cb + (size_t)m * 3840 + n0 + px;
        float4 v[4];
#pragma unroll
        for (int q = 0; q < 4; ++q) v[q] = *(const float4*)&sbias[oh + 4 * q];
#pragma unroll
        for (int i = 0; i < 5; ++i)
#pragma unroll
            for (int j = 0; j < 5; ++j) {
                float cv = crow[(size_t)(i * DIM) * 3840 + j * DIM];
                const float* th = &sth[(i * 5 + j) * 32 + oh];
#pragma unroll
                for (int q = 0; q < 4; ++q) {
                    float4 t4 = *(const float4*)&th[4 * q];
                    v[q].x = fmaf(cv, t4.x, v[q].x);
                    v[q].y = fmaf(cv, t4.y, v[q].y);
                    v[q].z = fmaf(cv, t4.z, v[q].z);
                    v[q].w = fmaf(cv, t4.w, v[q].w);
                }
            }
#pragma unroll
        for (int q = 0; q < 4; ++q) *(float4*)&As[px * 68 + oh + 4 * q] = v[q];
    }
    __syncthreads();

    const int px0 = tm * 8;
    float acc[8][4][2];
#pragma unroll
    for (int i = 0; i < 8; ++i)
#pragma unroll
        for (int g = 0; g < 4; ++g) { acc[i][g][0] = 0.f; acc[i][g][1] = 0.f; }

#pragma unroll 4
    for (int k = 0; k < 64; ++k) {
        float a[8]; float2 b[4];
#pragma unroll
        for (int i = 0; i < 8; ++i) a[i] = As[(px0 + i) * 68 + k];
#pragma unroll
        for (int g = 0; g < 4; ++g)
            b[g] = *(const float2*)&Bs[k * 132 + g * 32 + 2 * tn];
#pragma unroll
        for (int i = 0; i < 8; ++i)
#pragma unroll
            for (int g = 0; g < 4; ++g) {
                acc[i][g][0] = fmaf(a[i], b[g].x, acc[i][g][0]);
                acc[i][g][1] = fmaf(a[i], b[g].y, acc[i][g][1]);
            }
    }

    const float2 bgf = ((const float2*)bfv)[tn];
    const float2 bgi = ((const float2*)biv)[tn];
    const float2 bgo = ((const float2*)bov)[tn];
    const float2 bgc = ((const float2*)bcv)[tn];
    const float2 wo2 = ((const float2*)Wout)[tn];
    const float bo0 = bout[0];

#pragma unroll
    for (int i = 0; i < 8; ++i) {
        int p = pbase + px0 + i;
        float fx = sigm(acc[i][0][0] + bgf.x), fy = sigm(acc[i][0][1] + bgf.y);
        float ix = sigm(acc[i][1][0] + bgi.x), iy = sigm(acc[i][1][1] + bgi.y);
        float ox = sigm(acc[i][2][0] + bgo.x), oy = sigm(acc[i][2][1] + bgo.y);
        float gx = sigm(acc[i][3][0] + bgc.x), gy = sigm(acc[i][3][1] + bgc.y);
        float2 cold = *(const float2*)&c[(size_t)p * 32 + 2 * tn];
        float2 cn;
        cn.x = fx * cold.x + ix * gx;
        cn.y = fy * cold.y + iy * gy;
        float2 hn;
        hn.x = ox * sigm(cn.x);
        hn.y = oy * sigm(cn.y);
        *(float2*)&c[(size_t)p * 32 + 2 * tn] = cn;
        *(float2*)&h[(size_t)p * 32 + 2 * tn] = hn;
        float part = cn.x * wo2.x + cn.y * wo2.y;
        part += __shfl_xor(part, 1, 16);
        part += __shfl_xor(part, 2, 16);
        part += __shfl_xor(part, 4, 16);
        part += __shfl_xor(part, 8, 16);
        if (tn == 0) {
            float v = part + bo0;
            v = fminf(fmaxf(v, -15.f), 15.f);
            float e = __expf(2.f * v);
            x[p] += (e - 1.f) / (e + 1.f);
        }
    }
}

// ---------------------------------------------------------------------------
extern "C" void kernel_launch(void* const* d_in, const int* in_sizes, int n_in,
                              void* d_out, int out_size, void* d_ws, size_t ws_size,
                              hipStream_t stream)
{
    const float* x_in  = (const float*)d_in[0];
    const float* Lrow  = (const float*)d_in[1];
    const float* Lcol  = (const float*)d_in[2];
    const float* theta = (const float*)d_in[3];
    const float* bias  = (const float*)d_in[4];
    const float* Wf = (const float*)d_in[5];
    const float* Uf = (const float*)d_in[6];
    const float* bf = (const float*)d_in[7];
    const float* Wi = (const float*)d_in[8];
    const float* Ui = (const float*)d_in[9];
    const float* bi = (const float*)d_in[10];
    const float* Wo = (const float*)d_in[11];
    const float* Uo = (const float*)d_in[12];
    const float* bo = (const float*)d_in[13];
    const float* Wc = (const float*)d_in[14];
    const float* Uc = (const float*)d_in[15];
    const float* bc = (const float*)d_in[16];
    const float* Wout = (const float*)d_in[17];
    const float* bout = (const float*)d_in[18];
    (void)in_sizes; (void)n_in; (void)out_size;

    float* out = (float*)d_out;   // working x buffer

    // ---- workspace pool (263.06 MB total) ----
    // fp32: Cbig 14,745,600 | h 18,874,368 | c 18,874,368
    // shorts after: TrS0..2, TcS0..2, XRS0..2 (9 x 2,949,120)
    // aliases inside Cbig: TrV@0, TcV@+MXK*? (init only); xTS0..2 (per-iter head)
    float* ws   = (float*)d_ws;
    float* Cbig = ws;
    float* TrV  = Cbig;                 // init-phase alias
    float* TcV  = Cbig + STK;           // init-phase alias
    float* h    = ws + 14745600;
    float* c    = h + 18874368;
    unsigned short* sbase = (unsigned short*)(c + 18874368);
    unsigned short* TrS0 = sbase;
    unsigned short* TrS1 = TrS0 + STK;
    unsigned short* TrS2 = TrS1 + STK;
    unsigned short* TcS0 = TrS2 + STK;
    unsigned short* TcS1 = TcS0 + STK;
    unsigned short* TcS2 = TcS1 + STK;
    unsigned short* XRS0 = TcS2 + STK;
    unsigned short* XRS1 = XRS0 + STK;
    unsigned short* XRS2 = XRS1 + STK;
    unsigned short* xTS0 = (unsigned short*)Cbig;   // per-iter alias (C_big head)
    unsigned short* xTS1 = xTS0 + MXK;
    unsigned short* xTS2 = xTS1 + MXK;
    if (ws_size < (size_t)263061504) return;

    hipMemcpyAsync(out, x_in, (size_t)MXK * 4, hipMemcpyDeviceToDevice, stream);
    hipMemsetAsync(h, 0, (size_t)18874368 * 4, stream);
    hipMemsetAsync(c, 0, (size_t)18874368 * 4, stream);

    // ---- Chebyshev basis (fp32), vertical-stack row-major layout ----
    init_cheb_v<<<MXK / 256, 256, 0, stream>>>(Lrow, Lcol, TrV, TcV);
    for (int k = 2; k <= 4; ++k) {
        gemm2_f32<<<dim3(12, 12, 2), 256, 0, stream>>>(
            Lrow, TrV + (size_t)(k - 1) * MXK, TrV + (size_t)(k - 2) * MXK,
            TrV + (size_t)k * MXK,
            Lcol, TcV + (size_t)(k - 1) * MXK, TcV + (size_t)(k - 2) * MXK,
            TcV + (size_t)k * MXK,
            DIM, DIM, DIM, DIM, DIM, 2.0f, -1.0f);
    }
    // split to bf16x3 (TrV/TcV fp32 dead afterwards; region reused by C_big)
    cvt3<<<(STK / 4 + 255) / 256, 256, 0, stream>>>(TrV, TrS0, TrS1, TrS2, STK / 4);
    cvt3<<<(STK / 4 + 255) / 256, 256, 0, stream>>>(TcV, TcS0, TcS1, TcS2, STK / 4);

    for (int it = 0; it < 3; ++it) {
        // xT (bf16x3) = x^T
        transpose_cvt3<<<dim3(24, 24), 256, 0, stream>>>(out, xTS0, xTS1, xTS2);
        // stage1: XRv = TrV @ x  (M=3840, N=768, K=768), bf16x3 out
        gemm_bt_x3<<<dim3(6, 30), 256, 0, stream>>>(
            TrS0, TrS1, TrS2, xTS0, xTS1, xTS2,
            nullptr, XRS0, XRS1, XRS2, DIM, DIM, 1);
        // stage2: C_big = XRv @ TcV^T  (M=3840, N=3840, K=768), fp32 out
        gemm_bt_x3<<<dim3(30, 30), 256, 0, stream>>>(
            XRS0, XRS1, XRS2, TcS0, TcS1, TcS2,
            Cbig, nullptr, nullptr, nullptr, DIM, 3840, 0);
        // theta contraction + gates + state update + x += tanh(...)
        gate_theta_kernel<<<4608, 256, 0, stream>>>(
            Cbig, theta, bias,
            Wf, Wi, Wo, Wc, Uf, Ui, Uo, Uc,
            bf, bi, bo, bc, Wout, bout, h, c, out);
    }
}

// Round 4
// 2010.262 us; speedup vs baseline: 2.6546x; 1.4360x over previous
//
#include <hip/hip_runtime.h>
#include <hip/hip_bf16.h>
#include <stdint.h>

// ---------------------------------------------------------------------------
// MGCNN on MI355X — bf16x3 MFMA formulation, async-staged GEMM engine.
//
//   TrS/TcS[l]: bf16 split-l of T_0..T_4 stacked vertically (3840 x 768).
//   cheb  :  T_k = 2*(L @ T_{k-1}) - T_{k-2}         (mode 2, splits out)
//   stage1:  XRv[(i,m)][q] = sum_p T_i[m][p]*xT[q][p] (mode 1, splits out)
//   stage2:  C_big[(i,m)][(j,n)] = sum_q XRv[..]*TcV[..] (mode 0, fp32 out)
//   gate  :  theta-contract C_big -> xc(LDS) -> LSTM gates -> x += dx
//
// bf16x3: a = a1+a2+a3 (RNE splits); 6 products -> per-term error ~2^-25
// (fp32-grade; absmax matched fp32 baseline exactly in R3).
// ---------------------------------------------------------------------------

#define DIM 768
#define MXK 589824        // 768*768
#define STK 2949120       // 5*768*768

typedef short bf16x8 __attribute__((ext_vector_type(8)));
typedef float f32x4 __attribute__((ext_vector_type(4)));
typedef unsigned short ushort_t;

__device__ __forceinline__ float sigm(float v) {
    return 1.0f / (1.0f + __expf(-v));
}
__device__ __forceinline__ unsigned short f2bf(float f) {
    unsigned u = __float_as_uint(f);
    return (unsigned short)((u + 0x7FFF + ((u >> 16) & 1)) >> 16);
}
__device__ __forceinline__ float bf2f(unsigned short b) {
    return __uint_as_float(((unsigned)b) << 16);
}
__device__ __forceinline__ void split3(float f, unsigned short& h1,
                                       unsigned short& h2, unsigned short& h3) {
    h1 = f2bf(f);
    float r = f - bf2f(h1);
    h2 = f2bf(r);
    float r2 = r - bf2f(h2);
    h3 = f2bf(r2);
}

// async 16B global->LDS (CK-style addrspace casts; LDS dest = base+lane*16)
__device__ __forceinline__ void gl_lds16(const unsigned short* g,
                                         unsigned short* l) {
    auto gp = reinterpret_cast<const __attribute__((address_space(1))) uint32_t*>(
        reinterpret_cast<uintptr_t>(g));
    auto lp = reinterpret_cast<__attribute__((address_space(3))) uint32_t*>(
        reinterpret_cast<uintptr_t>(l));
    __builtin_amdgcn_global_load_lds(gp, lp, 16, 0, 0);
}

// ---------------------------------------------------------------------------
// init: T0 = I, T1 = L  ->  bf16x3 splits, for both Tr (L_row) and Tc (L_col)
// ---------------------------------------------------------------------------
__global__ __launch_bounds__(256) void init_split(
    const float* __restrict__ Lrow, const float* __restrict__ Lcol,
    ushort_t* __restrict__ TrS0, ushort_t* __restrict__ TrS1,
    ushort_t* __restrict__ TrS2,
    ushort_t* __restrict__ TcS0, ushort_t* __restrict__ TcS1,
    ushort_t* __restrict__ TcS2)
{
    int idx = blockIdx.x * 256 + threadIdx.x;      // 0 .. 768*768-1
    int p = idx / DIM, m = idx % DIM;
    unsigned short eye = (p == m) ? 0x3F80 : 0;
    TrS0[idx] = eye; TrS1[idx] = 0; TrS2[idx] = 0;
    TcS0[idx] = eye; TcS1[idx] = 0; TcS2[idx] = 0;
    unsigned short h1, h2, h3;
    split3(Lrow[idx], h1, h2, h3);
    TrS0[MXK + idx] = h1; TrS1[MXK + idx] = h2; TrS2[MXK + idx] = h3;
    split3(Lcol[idx], h1, h2, h3);
    TcS0[MXK + idx] = h1; TcS1[MXK + idx] = h2; TcS2[MXK + idx] = h3;
}

// ---------------------------------------------------------------------------
// transpose 768x768 + bf16x3 split:  xT[q][p] = x[p][q]  (3 short outputs)
// ---------------------------------------------------------------------------
__global__ __launch_bounds__(256) void transpose_cvt3(
    const float* __restrict__ in, ushort_t* __restrict__ o1,
    ushort_t* __restrict__ o2, ushort_t* __restrict__ o3)
{
    __shared__ float t[32][33];
    int x = threadIdx.x & 31, y = threadIdx.x >> 5;   // y: 0..7
    int bx = blockIdx.x * 32, by = blockIdx.y * 32;
#pragma unroll
    for (int r = 0; r < 4; ++r)
        t[y + 8 * r][x] = in[(size_t)(by + y + 8 * r) * DIM + bx + x];
    __syncthreads();
#pragma unroll
    for (int r = 0; r < 4; ++r) {
        float v = t[x][y + 8 * r];
        unsigned short h1, h2, h3;
        split3(v, h1, h2, h3);
        size_t o = (size_t)(bx + y + 8 * r) * DIM + by + x;
        o1[o] = h1; o2[o] = h2; o3[o] = h3;
    }
}

// ---------------------------------------------------------------------------
// bf16x3 MFMA GEMM engine, B-transposed inputs (both operands k-contiguous):
//   acc[m][n] = sum_k A[m][k] * BT[n][k]
// 128x128 tile, BK=32, 4 waves each 64x64 via 4x4 16x16x32 MFMA frags.
// Staging: global_load_lds x16B, chunk-XOR-swizzled LDS ((c = p ^ (r&3))).
// mode 0: C fp32 (ldc), flat grid w/ supertile swizzle (nbx columns)
// mode 1: bf16x3 epilogue -> D1/D2/D3 (ldc)
// mode 2: cheb: v = 2*acc - (P1+P2+P3 reconstructed); bf16x3 -> D1/D2/D3
// ---------------------------------------------------------------------------
__global__ __launch_bounds__(256) void gemm_bt_x3(
    const ushort_t* __restrict__ A1, const ushort_t* __restrict__ A2,
    const ushort_t* __restrict__ A3,
    const ushort_t* __restrict__ B1, const ushort_t* __restrict__ B2,
    const ushort_t* __restrict__ B3,
    const ushort_t* __restrict__ P1, const ushort_t* __restrict__ P2,
    const ushort_t* __restrict__ P3,
    float* __restrict__ C,
    ushort_t* __restrict__ D1, ushort_t* __restrict__ D2,
    ushort_t* __restrict__ D3,
    int K, int ldc, int mode, int nbx)
{
    __shared__ __align__(16) ushort_t sA[3][128 * 32];
    __shared__ __align__(16) ushort_t sB[3][128 * 32];

    const int tid = threadIdx.x;

    int bx, by;
    if (mode == 0) {
        // supertile decode: stride-8 block ids share bx -> per-XCD L2 reuse
        int g = blockIdx.x;
        int sup = g / 240;                 // 8 rows x 30 cols per supertile
        int rows0 = sup * 8;
        int H = 30 - rows0; if (H > 8) H = 8;
        int local = g - rows0 * 30;
        by = rows0 + local % H;
        bx = local / H;
    } else {
        bx = blockIdx.x % nbx;
        by = blockIdx.x / nbx;
    }
    const int m0 = by * 128, n0 = bx * 128;

    const int lane = tid & 63, w4 = tid >> 6;
    const int wm = (w4 & 1) * 64, wn = (w4 >> 1) * 64;
    const int lm = lane & 15, quad = lane >> 4;
    const int psw = (quad ^ (lm & 3)) * 8;   // swizzled chunk offset (shorts)

    // staging metadata: two 16B slots per thread per buffer
    const int L0 = w4 * 128 + lane, L1 = L0 + 64;
    const int r0 = L0 >> 2, c0 = (L0 & 3) ^ (r0 & 3);
    const int r1 = L1 >> 2, c1 = (L1 & 3) ^ (r1 & 3);

    const ushort_t* gA[3][2];
    const ushort_t* gB[3][2];
    const ushort_t* Asrc[3] = {A1, A2, A3};
    const ushort_t* Bsrc[3] = {B1, B2, B3};
#pragma unroll
    for (int l = 0; l < 3; ++l) {
        gA[l][0] = Asrc[l] + (size_t)(m0 + r0) * K + c0 * 8;
        gA[l][1] = Asrc[l] + (size_t)(m0 + r1) * K + c1 * 8;
        gB[l][0] = Bsrc[l] + (size_t)(n0 + r0) * K + c0 * 8;
        gB[l][1] = Bsrc[l] + (size_t)(n0 + r1) * K + c1 * 8;
    }
    ushort_t* dA[3][2];
    ushort_t* dB[3][2];
#pragma unroll
    for (int l = 0; l < 3; ++l) {
        dA[l][0] = &sA[l][w4 * 1024];
        dA[l][1] = &sA[l][w4 * 1024 + 512];
        dB[l][0] = &sB[l][w4 * 1024];
        dB[l][1] = &sB[l][w4 * 1024 + 512];
    }

    f32x4 acc[4][4] = {};

    for (int kb = 0; kb < K; kb += 32) {
#pragma unroll
        for (int l = 0; l < 3; ++l) {
            gl_lds16(gA[l][0] + kb, dA[l][0]);
            gl_lds16(gA[l][1] + kb, dA[l][1]);
            gl_lds16(gB[l][0] + kb, dB[l][0]);
            gl_lds16(gB[l][1] + kb, dB[l][1]);
        }
        __syncthreads();   // drains vmcnt -> staged data visible

        bf16x8 bfr[3][4];
#pragma unroll
        for (int l = 0; l < 3; ++l)
#pragma unroll
            for (int fn = 0; fn < 4; ++fn)
                bfr[l][fn] = *(const bf16x8*)&sB[l][(wn + fn * 16 + lm) * 32 + psw];
#pragma unroll
        for (int fm = 0; fm < 4; ++fm) {
            const int ar = (wm + fm * 16 + lm) * 32 + psw;
            bf16x8 a1 = *(const bf16x8*)&sA[0][ar];
            bf16x8 a2 = *(const bf16x8*)&sA[1][ar];
            bf16x8 a3 = *(const bf16x8*)&sA[2][ar];
#pragma unroll
            for (int fn = 0; fn < 4; ++fn) {
                f32x4 a = acc[fm][fn];
                // smallest-magnitude products first
                a = __builtin_amdgcn_mfma_f32_16x16x32_bf16(a3, bfr[0][fn], a, 0, 0, 0);
                a = __builtin_amdgcn_mfma_f32_16x16x32_bf16(a1, bfr[2][fn], a, 0, 0, 0);
                a = __builtin_amdgcn_mfma_f32_16x16x32_bf16(a2, bfr[1][fn], a, 0, 0, 0);
                a = __builtin_amdgcn_mfma_f32_16x16x32_bf16(a2, bfr[0][fn], a, 0, 0, 0);
                a = __builtin_amdgcn_mfma_f32_16x16x32_bf16(a1, bfr[1][fn], a, 0, 0, 0);
                a = __builtin_amdgcn_mfma_f32_16x16x32_bf16(a1, bfr[0][fn], a, 0, 0, 0);
                acc[fm][fn] = a;
            }
        }
        __syncthreads();   // all reads done before next chunk's async writes
    }

    // epilogue: C/D layout col=lane&15, row=quad*4+reg  [verified m89/m91]
#pragma unroll
    for (int fm = 0; fm < 4; ++fm)
#pragma unroll
        for (int fn = 0; fn < 4; ++fn) {
            f32x4 v = acc[fm][fn];
            int col = n0 + wn + fn * 16 + lm;
#pragma unroll
            for (int r = 0; r < 4; ++r) {
                int row = m0 + wm + fm * 16 + quad * 4 + r;
                size_t o = (size_t)row * ldc + col;
                if (mode == 0) {
                    C[o] = v[r];
                } else {
                    float val = v[r];
                    if (mode == 2)
                        val = 2.0f * val -
                              (bf2f(P1[o]) + bf2f(P2[o]) + bf2f(P3[o]));
                    unsigned short h1, h2, h3;
                    split3(val, h1, h2, h3);
                    D1[o] = h1; D2[o] = h2; D3[o] = h3;
                }
            }
        }
}

// ---------------------------------------------------------------------------
// Gate kernel with fused theta contraction.
// Block = 128 pixels of one row m: m = blk/6, n0 = (blk%6)*128.
//   xc[px][o] = sum_ij C_big[i*768+m][j*768+n0+px] * theta[ij][o] + bias[o]
// then GEMM [xc|h](128x64) @ [W;U](64x128) + LSTM elementwise + x += dx.
// ---------------------------------------------------------------------------
__global__ __launch_bounds__(256) void gate_theta_kernel(
    const float* __restrict__ Cb, const float* __restrict__ theta,
    const float* __restrict__ bias,
    const float* __restrict__ Wf, const float* __restrict__ Wi,
    const float* __restrict__ Wo, const float* __restrict__ Wc,
    const float* __restrict__ Uf, const float* __restrict__ Ui,
    const float* __restrict__ Uo, const float* __restrict__ Uc,
    const float* __restrict__ bfv, const float* __restrict__ biv,
    const float* __restrict__ bov, const float* __restrict__ bcv,
    const float* __restrict__ Wout, const float* __restrict__ bout,
    float* __restrict__ h, float* __restrict__ c, float* __restrict__ x)
{
    __shared__ float As[128 * 68];   // [px][k], k<32: xc, k>=32: h
    __shared__ float Bs[64 * 132];   // [k][g*32+o]
    __shared__ float sth[800];
    __shared__ float sbias[32];

    const int tid = threadIdx.x;
    const int tn = tid & 15, tm = tid >> 4;
    const int m = blockIdx.x / 6;
    const int n0 = (blockIdx.x % 6) * 128;
    const int pbase = m * DIM + n0;

    for (int t = tid; t < 800; t += 256) sth[t] = theta[t];
    if (tid < 32) sbias[tid] = bias[tid];

    // stage h -> As[px][32..63]  (128 px * 8 float4 = 1024)
    const float4* h4g = (const float4*)h;
#pragma unroll
    for (int cc = 0; cc < 4; ++cc) {
        int idx = cc * 256 + tid;          // 0..1023
        int px = idx >> 3, q = idx & 7;
        *(float4*)&As[px * 68 + 32 + 4 * q] = h4g[(size_t)(pbase + px) * 8 + q];
    }
    // stage weights
    const float* WU[8] = {Wf, Wi, Wo, Wc, Uf, Ui, Uo, Uc};
#pragma unroll
    for (int cc = 0; cc < 8; ++cc) {
        int t = cc * 256 + tid;
        int kk = t >> 5;
        int gq = t & 31; int g = gq >> 3, q = gq & 7;
        const float* src = (kk < 32) ? WU[g] : WU[4 + g];
        float4 v = *(const float4*)&src[(kk & 31) * 32 + 4 * q];
        *(float4*)&Bs[kk * 132 + g * 32 + 4 * q] = v;
    }
    __syncthreads();   // sth/sbias ready

    // theta contraction: thread covers (px = tid&127, o-half = (tid>>7)*16)
    {
        int px = tid & 127;
        int oh = (tid >> 7) * 16;
        const float* crow = Cb + (size_t)m * 3840 + n0 + px;
        float4 v[4];
#pragma unroll
        for (int q = 0; q < 4; ++q) v[q] = *(const float4*)&sbias[oh + 4 * q];
#pragma unroll
        for (int i = 0; i < 5; ++i)
#pragma unroll
            for (int j = 0; j < 5; ++j) {
                float cv = crow[(size_t)(i * DIM) * 3840 + j * DIM];
                const float* th = &sth[(i * 5 + j) * 32 + oh];
#pragma unroll
                for (int q = 0; q < 4; ++q) {
                    float4 t4 = *(const float4*)&th[4 * q];
                    v[q].x = fmaf(cv, t4.x, v[q].x);
                    v[q].y = fmaf(cv, t4.y, v[q].y);
                    v[q].z = fmaf(cv, t4.z, v[q].z);
                    v[q].w = fmaf(cv, t4.w, v[q].w);
                }
            }
#pragma unroll
        for (int q = 0; q < 4; ++q) *(float4*)&As[px * 68 + oh + 4 * q] = v[q];
    }
    __syncthreads();

    const int px0 = tm * 8;
    float acc[8][4][2];
#pragma unroll
    for (int i = 0; i < 8; ++i)
#pragma unroll
        for (int g = 0; g < 4; ++g) { acc[i][g][0] = 0.f; acc[i][g][1] = 0.f; }

#pragma unroll 4
    for (int k = 0; k < 64; ++k) {
        float a[8]; float2 b[4];
#pragma unroll
        for (int i = 0; i < 8; ++i) a[i] = As[(px0 + i) * 68 + k];
#pragma unroll
        for (int g = 0; g < 4; ++g)
            b[g] = *(const float2*)&Bs[k * 132 + g * 32 + 2 * tn];
#pragma unroll
        for (int i = 0; i < 8; ++i)
#pragma unroll
            for (int g = 0; g < 4; ++g) {
                acc[i][g][0] = fmaf(a[i], b[g].x, acc[i][g][0]);
                acc[i][g][1] = fmaf(a[i], b[g].y, acc[i][g][1]);
            }
    }

    const float2 bgf = ((const float2*)bfv)[tn];
    const float2 bgi = ((const float2*)biv)[tn];
    const float2 bgo = ((const float2*)bov)[tn];
    const float2 bgc = ((const float2*)bcv)[tn];
    const float2 wo2 = ((const float2*)Wout)[tn];
    const float bo0 = bout[0];

#pragma unroll
    for (int i = 0; i < 8; ++i) {
        int p = pbase + px0 + i;
        float fx = sigm(acc[i][0][0] + bgf.x), fy = sigm(acc[i][0][1] + bgf.y);
        float ix = sigm(acc[i][1][0] + bgi.x), iy = sigm(acc[i][1][1] + bgi.y);
        float ox = sigm(acc[i][2][0] + bgo.x), oy = sigm(acc[i][2][1] + bgo.y);
        float gx = sigm(acc[i][3][0] + bgc.x), gy = sigm(acc[i][3][1] + bgc.y);
        float2 cold = *(const float2*)&c[(size_t)p * 32 + 2 * tn];
        float2 cn;
        cn.x = fx * cold.x + ix * gx;
        cn.y = fy * cold.y + iy * gy;
        float2 hn;
        hn.x = ox * sigm(cn.x);
        hn.y = oy * sigm(cn.y);
        *(float2*)&c[(size_t)p * 32 + 2 * tn] = cn;
        *(float2*)&h[(size_t)p * 32 + 2 * tn] = hn;
        float part = cn.x * wo2.x + cn.y * wo2.y;
        part += __shfl_xor(part, 1, 16);
        part += __shfl_xor(part, 2, 16);
        part += __shfl_xor(part, 4, 16);
        part += __shfl_xor(part, 8, 16);
        if (tn == 0) {
            float v = part + bo0;
            v = fminf(fmaxf(v, -15.f), 15.f);
            float e = __expf(2.f * v);
            x[p] += (e - 1.f) / (e + 1.f);
        }
    }
}

// ---------------------------------------------------------------------------
extern "C" void kernel_launch(void* const* d_in, const int* in_sizes, int n_in,
                              void* d_out, int out_size, void* d_ws, size_t ws_size,
                              hipStream_t stream)
{
    const float* x_in  = (const float*)d_in[0];
    const float* Lrow  = (const float*)d_in[1];
    const float* Lcol  = (const float*)d_in[2];
    const float* theta = (const float*)d_in[3];
    const float* bias  = (const float*)d_in[4];
    const float* Wf = (const float*)d_in[5];
    const float* Uf = (const float*)d_in[6];
    const float* bf = (const float*)d_in[7];
    const float* Wi = (const float*)d_in[8];
    const float* Ui = (const float*)d_in[9];
    const float* bi = (const float*)d_in[10];
    const float* Wo = (const float*)d_in[11];
    const float* Uo = (const float*)d_in[12];
    const float* bo = (const float*)d_in[13];
    const float* Wc = (const float*)d_in[14];
    const float* Uc = (const float*)d_in[15];
    const float* bc = (const float*)d_in[16];
    const float* Wout = (const float*)d_in[17];
    const float* bout = (const float*)d_in[18];
    (void)in_sizes; (void)n_in; (void)out_size;

    float* out = (float*)d_out;   // working x buffer

    // ---- workspace pool (263.06 MB total) ----
    float* ws   = (float*)d_ws;
    float* Cbig = ws;                                // 14,745,600 f (59 MB)
    float* h    = ws + 14745600;                     // 18,874,368 f
    float* c    = h + 18874368;                      // 18,874,368 f
    ushort_t* sbase = (ushort_t*)(c + 18874368);
    ushort_t* TrS0 = sbase;                          // 5-level Cheb stacks
    ushort_t* TrS1 = TrS0 + STK;
    ushort_t* TrS2 = TrS1 + STK;
    ushort_t* TcS0 = TrS2 + STK;
    ushort_t* TcS1 = TcS0 + STK;
    ushort_t* TcS2 = TcS1 + STK;
    ushort_t* XRS0 = TcS2 + STK;
    ushort_t* XRS1 = XRS0 + STK;
    ushort_t* XRS2 = XRS1 + STK;
    ushort_t* xTS0 = (ushort_t*)Cbig;                // per-iter alias (dead
    ushort_t* xTS1 = xTS0 + MXK;                     //  before stage2 writes)
    ushort_t* xTS2 = xTS1 + MXK;
    if (ws_size < (size_t)263061504) return;

    hipMemcpyAsync(out, x_in, (size_t)MXK * 4, hipMemcpyDeviceToDevice, stream);
    hipMemsetAsync(h, 0, (size_t)18874368 * 4, stream);
    hipMemsetAsync(c, 0, (size_t)18874368 * 4, stream);

    // ---- Chebyshev basis entirely in split domain ----
    init_split<<<MXK / 256, 256, 0, stream>>>(Lrow, Lcol,
                                              TrS0, TrS1, TrS2, TcS0, TcS1, TcS2);
    for (int k = 2; k <= 4; ++k) {
        // T_k = 2*L@T_{k-1} - T_{k-2}; A = T_1 (= L) splits; all symmetric
        gemm_bt_x3<<<36, 256, 0, stream>>>(
            TrS0 + MXK, TrS1 + MXK, TrS2 + MXK,
            TrS0 + (size_t)(k - 1) * MXK, TrS1 + (size_t)(k - 1) * MXK,
            TrS2 + (size_t)(k - 1) * MXK,
            TrS0 + (size_t)(k - 2) * MXK, TrS1 + (size_t)(k - 2) * MXK,
            TrS2 + (size_t)(k - 2) * MXK,
            nullptr,
            TrS0 + (size_t)k * MXK, TrS1 + (size_t)k * MXK,
            TrS2 + (size_t)k * MXK,
            DIM, DIM, 2, 6);
        gemm_bt_x3<<<36, 256, 0, stream>>>(
            TcS0 + MXK, TcS1 + MXK, TcS2 + MXK,
            TcS0 + (size_t)(k - 1) * MXK, TcS1 + (size_t)(k - 1) * MXK,
            TcS2 + (size_t)(k - 1) * MXK,
            TcS0 + (size_t)(k - 2) * MXK, TcS1 + (size_t)(k - 2) * MXK,
            TcS2 + (size_t)(k - 2) * MXK,
            nullptr,
            TcS0 + (size_t)k * MXK, TcS1 + (size_t)k * MXK,
            TcS2 + (size_t)k * MXK,
            DIM, DIM, 2, 6);
    }

    for (int it = 0; it < 3; ++it) {
        // xT (bf16x3) = x^T
        transpose_cvt3<<<dim3(24, 24), 256, 0, stream>>>(out, xTS0, xTS1, xTS2);
        // stage1: XRv = TrV @ x  (M=3840, N=768, K=768), bf16x3 out
        gemm_bt_x3<<<180, 256, 0, stream>>>(
            TrS0, TrS1, TrS2, xTS0, xTS1, xTS2,
            nullptr, nullptr, nullptr,
            nullptr, XRS0, XRS1, XRS2, DIM, DIM, 1, 6);
        // stage2: C_big = XRv @ TcV^T  (M=3840, N=3840, K=768), fp32 out
        gemm_bt_x3<<<900, 256, 0, stream>>>(
            XRS0, XRS1, XRS2, TcS0, TcS1, TcS2,
            nullptr, nullptr, nullptr,
            Cbig, nullptr, nullptr, nullptr, DIM, 3840, 0, 30);
        // theta contraction + gates + state update + x += tanh(...)
        gate_theta_kernel<<<4608, 256, 0, stream>>>(
            Cbig, theta, bias,
            Wf, Wi, Wo, Wc, Uf, Ui, Uo, Uc,
            bf, bi, bo, bc, Wout, bout, h, c, out);
    }
}

// Round 5
// 1157.797 us; speedup vs baseline: 4.6091x; 1.7363x over previous
//
#include <hip/hip_runtime.h>
#include <hip/hip_bf16.h>
#include <stdint.h>

// ---------------------------------------------------------------------------
// MGCNN on MI355X — bf16x3 MFMA conv + MFMA gate kernel.
//
//   S_l levels hold Tr stack (rows 0..3839) and Tc stack (rows 3840..7679).
//   cheb  :  T_k = 2*(L @ T_{k-1}) - T_{k-2}          (mode 2, both stacks)
//   stage1:  XRv[(i,m)][q] = sum_p T_i[m][p]*xT[q][p]  (mode 1, splits out)
//   stage2:  C_big[(i,m)][(j,n)] = sum_q XRv[..]*TcV[..] (mode 0, fp32 out)
//   gate  :  theta-contract C_big -> xc(LDS bf16x2) -> MFMA vs weight stack
//            -> LSTM elementwise in-register -> c(f32), h(bf16x2), x += dx
// ---------------------------------------------------------------------------

#define DIM 768
#define MXK 589824        // 768*768
#define STK 2949120       // 5*768*768

typedef short bf16x8 __attribute__((ext_vector_type(8)));
typedef float f32x4 __attribute__((ext_vector_type(4)));
typedef unsigned short ushort_t;

__device__ __forceinline__ float sigm(float v) {
    return 1.0f / (1.0f + __expf(-v));
}
__device__ __forceinline__ unsigned short f2bf(float f) {
    unsigned u = __float_as_uint(f);
    return (unsigned short)((u + 0x7FFF + ((u >> 16) & 1)) >> 16);
}
__device__ __forceinline__ float bf2f(unsigned short b) {
    return __uint_as_float(((unsigned)b) << 16);
}
__device__ __forceinline__ void split3(float f, unsigned short& h1,
                                       unsigned short& h2, unsigned short& h3) {
    h1 = f2bf(f);
    float r = f - bf2f(h1);
    h2 = f2bf(r);
    float r2 = r - bf2f(h2);
    h3 = f2bf(r2);
}

// async 16B global->LDS
__device__ __forceinline__ void gl_lds16(const unsigned short* g,
                                         unsigned short* l) {
    auto gp = reinterpret_cast<const __attribute__((address_space(1))) uint32_t*>(
        reinterpret_cast<uintptr_t>(g));
    auto lp = reinterpret_cast<__attribute__((address_space(3))) uint32_t*>(
        reinterpret_cast<uintptr_t>(l));
    __builtin_amdgcn_global_load_lds(gp, lp, 16, 0, 0);
}

// ---------------------------------------------------------------------------
// init: T0 = I, T1 = L  ->  bf16x3 splits, Tr stack then Tc stack per level
// ---------------------------------------------------------------------------
__global__ __launch_bounds__(256) void init_split(
    const float* __restrict__ Lrow, const float* __restrict__ Lcol,
    ushort_t* __restrict__ S0, ushort_t* __restrict__ S1,
    ushort_t* __restrict__ S2)
{
    int idx = blockIdx.x * 256 + threadIdx.x;      // 0 .. 768*768-1
    int p = idx / DIM, m = idx % DIM;
    unsigned short eye = (p == m) ? 0x3F80 : 0;
    S0[idx] = eye; S1[idx] = 0; S2[idx] = 0;                 // Tr T0
    S0[STK + idx] = eye; S1[STK + idx] = 0; S2[STK + idx] = 0; // Tc T0
    unsigned short h1, h2, h3;
    split3(Lrow[idx], h1, h2, h3);
    S0[MXK + idx] = h1; S1[MXK + idx] = h2; S2[MXK + idx] = h3;
    split3(Lcol[idx], h1, h2, h3);
    S0[STK + MXK + idx] = h1; S1[STK + MXK + idx] = h2; S2[STK + MXK + idx] = h3;
}

// ---------------------------------------------------------------------------
// weight stack prep: Wstack[R][k] bf16, R in 0..127, k in 0..63
//   g = (R>>4)&3 (gate f,i,o,c), o = (R>>6)*16 + (R&15)
//   k<32: W_g[k][o], k>=32: U_g[k-32][o]
// ---------------------------------------------------------------------------
__global__ __launch_bounds__(256) void prep_gate_weights(
    const float* __restrict__ Wf, const float* __restrict__ Wi,
    const float* __restrict__ Wo, const float* __restrict__ Wc,
    const float* __restrict__ Uf, const float* __restrict__ Ui,
    const float* __restrict__ Uo, const float* __restrict__ Uc,
    ushort_t* __restrict__ Wstack)
{
    int idx = blockIdx.x * 256 + threadIdx.x;
    if (idx >= 8192) return;
    int R = idx >> 6, k = idx & 63;
    int g = (R >> 4) & 3, o = (R >> 6) * 16 + (R & 15);
    const float* Wg[4] = {Wf, Wi, Wo, Wc};
    const float* Ug[4] = {Uf, Ui, Uo, Uc};
    float v = (k < 32) ? Wg[g][k * 32 + o] : Ug[g][(k - 32) * 32 + o];
    Wstack[idx] = f2bf(v);
}

// ---------------------------------------------------------------------------
// transpose 768x768 + bf16x3 split:  xT[q][p] = x[p][q]
// ---------------------------------------------------------------------------
__global__ __launch_bounds__(256) void transpose_cvt3(
    const float* __restrict__ in, ushort_t* __restrict__ o1,
    ushort_t* __restrict__ o2, ushort_t* __restrict__ o3)
{
    __shared__ float t[32][33];
    int x = threadIdx.x & 31, y = threadIdx.x >> 5;
    int bx = blockIdx.x * 32, by = blockIdx.y * 32;
#pragma unroll
    for (int r = 0; r < 4; ++r)
        t[y + 8 * r][x] = in[(size_t)(by + y + 8 * r) * DIM + bx + x];
    __syncthreads();
#pragma unroll
    for (int r = 0; r < 4; ++r) {
        float v = t[x][y + 8 * r];
        unsigned short h1, h2, h3;
        split3(v, h1, h2, h3);
        size_t o = (size_t)(bx + y + 8 * r) * DIM + by + x;
        o1[o] = h1; o2[o] = h2; o3[o] = h3;
    }
}

// ---------------------------------------------------------------------------
// bf16x3 MFMA GEMM engine (B-transposed, k-contig), 128x128 tile, BK=32.
// LDS chunk swizzle s(r) = (r>>1)&3  -> 2-way (free) ds_read_b128 banks.
// mode 0: C fp32, supertile grid; mode 1: bf16x3 out; mode 2: cheb
// (v = 2*acc - P), dual-stack via halfStride when blockIdx covers 2 grids.
// ---------------------------------------------------------------------------
__global__ __launch_bounds__(256) void gemm_bt_x3(
    const ushort_t* __restrict__ A1, const ushort_t* __restrict__ A2,
    const ushort_t* __restrict__ A3,
    const ushort_t* __restrict__ B1, const ushort_t* __restrict__ B2,
    const ushort_t* __restrict__ B3,
    const ushort_t* __restrict__ P1, const ushort_t* __restrict__ P2,
    const ushort_t* __restrict__ P3,
    float* __restrict__ C,
    ushort_t* __restrict__ D1, ushort_t* __restrict__ D2,
    ushort_t* __restrict__ D3,
    int K, int ldc, int mode, int nbx, int halfStride)
{
    __shared__ __align__(16) ushort_t sA[3][128 * 32];
    __shared__ __align__(16) ushort_t sB[3][128 * 32];

    const int tid = threadIdx.x;

    int bx, by;
    size_t hoff = 0;
    if (mode == 0) {
        int g = blockIdx.x;
        int sup = g / 240;
        int rows0 = sup * 8;
        int H = 30 - rows0; if (H > 8) H = 8;
        int local = g - rows0 * 30;
        by = rows0 + local % H;
        bx = local / H;
    } else {
        bx = blockIdx.x % nbx;
        by = blockIdx.x / nbx;
        if (mode == 2 && by >= 6) { by -= 6; hoff = (size_t)halfStride; }
    }
    const int m0 = by * 128, n0 = bx * 128;

    const int lane = tid & 63, w4 = tid >> 6;
    const int wm = (w4 & 1) * 64, wn = (w4 >> 1) * 64;
    const int lm = lane & 15, quad = lane >> 4;
    const int psw = (quad ^ ((lm >> 1) & 3)) * 8;   // swizzled chunk (shorts)

    const int L0 = w4 * 128 + lane, L1 = L0 + 64;
    const int r0 = L0 >> 2, c0 = (L0 & 3) ^ ((r0 >> 1) & 3);
    const int r1 = L1 >> 2, c1 = (L1 & 3) ^ ((r1 >> 1) & 3);

    const ushort_t* gA[3][2];
    const ushort_t* gB[3][2];
    const ushort_t* Asrc[3] = {A1 + hoff, A2 + hoff, A3 + hoff};
    const ushort_t* Bsrc[3] = {B1 + hoff, B2 + hoff, B3 + hoff};
#pragma unroll
    for (int l = 0; l < 3; ++l) {
        gA[l][0] = Asrc[l] + (size_t)(m0 + r0) * K + c0 * 8;
        gA[l][1] = Asrc[l] + (size_t)(m0 + r1) * K + c1 * 8;
        gB[l][0] = Bsrc[l] + (size_t)(n0 + r0) * K + c0 * 8;
        gB[l][1] = Bsrc[l] + (size_t)(n0 + r1) * K + c1 * 8;
    }
    ushort_t* dA[3][2];
    ushort_t* dB[3][2];
#pragma unroll
    for (int l = 0; l < 3; ++l) {
        dA[l][0] = &sA[l][w4 * 1024];
        dA[l][1] = &sA[l][w4 * 1024 + 512];
        dB[l][0] = &sB[l][w4 * 1024];
        dB[l][1] = &sB[l][w4 * 1024 + 512];
    }

    f32x4 acc[4][4] = {};

    for (int kb = 0; kb < K; kb += 32) {
#pragma unroll
        for (int l = 0; l < 3; ++l) {
            gl_lds16(gA[l][0] + kb, dA[l][0]);
            gl_lds16(gA[l][1] + kb, dA[l][1]);
            gl_lds16(gB[l][0] + kb, dB[l][0]);
            gl_lds16(gB[l][1] + kb, dB[l][1]);
        }
        __syncthreads();

        bf16x8 bfr[3][4];
#pragma unroll
        for (int l = 0; l < 3; ++l)
#pragma unroll
            for (int fn = 0; fn < 4; ++fn)
                bfr[l][fn] = *(const bf16x8*)&sB[l][(wn + fn * 16 + lm) * 32 + psw];
#pragma unroll
        for (int fm = 0; fm < 4; ++fm) {
            const int ar = (wm + fm * 16 + lm) * 32 + psw;
            bf16x8 a1 = *(const bf16x8*)&sA[0][ar];
            bf16x8 a2 = *(const bf16x8*)&sA[1][ar];
            bf16x8 a3 = *(const bf16x8*)&sA[2][ar];
#pragma unroll
            for (int fn = 0; fn < 4; ++fn) {
                f32x4 a = acc[fm][fn];
                a = __builtin_amdgcn_mfma_f32_16x16x32_bf16(a3, bfr[0][fn], a, 0, 0, 0);
                a = __builtin_amdgcn_mfma_f32_16x16x32_bf16(a1, bfr[2][fn], a, 0, 0, 0);
                a = __builtin_amdgcn_mfma_f32_16x16x32_bf16(a2, bfr[1][fn], a, 0, 0, 0);
                a = __builtin_amdgcn_mfma_f32_16x16x32_bf16(a2, bfr[0][fn], a, 0, 0, 0);
                a = __builtin_amdgcn_mfma_f32_16x16x32_bf16(a1, bfr[1][fn], a, 0, 0, 0);
                a = __builtin_amdgcn_mfma_f32_16x16x32_bf16(a1, bfr[0][fn], a, 0, 0, 0);
                acc[fm][fn] = a;
            }
        }
        __syncthreads();
    }

    // epilogue: C/D layout col=lane&15, row=quad*4+reg  [verified m89/m91]
#pragma unroll
    for (int fm = 0; fm < 4; ++fm)
#pragma unroll
        for (int fn = 0; fn < 4; ++fn) {
            f32x4 v = acc[fm][fn];
            int col = n0 + wn + fn * 16 + lm;
#pragma unroll
            for (int r = 0; r < 4; ++r) {
                int row = m0 + wm + fm * 16 + quad * 4 + r;
                size_t o = (size_t)row * ldc + col;
                if (mode == 0) {
                    C[o] = v[r];
                } else {
                    float val = v[r];
                    if (mode == 2)
                        val = 2.0f * val -
                              (bf2f(P1[hoff + o]) + bf2f(P2[hoff + o]) +
                               bf2f(P3[hoff + o]));
                    unsigned short h1, h2, h3;
                    split3(val, h1, h2, h3);
                    D1[hoff + o] = h1; D2[hoff + o] = h2; D3[hoff + o] = h3;
                }
            }
        }
}

// ---------------------------------------------------------------------------
// MFMA gate kernel. Block = 128 pixels (m = blk/6, n0 = (blk%6)*128).
//  1) theta-contract C_big -> xc[px][32], split bf16x2 into sB (k 0..31)
//  2) h (bf16x2 global) -> sB k 32..63 (zeros if first)
//  3) MFMA: A = Wstack rows R (channels, from global), B = sB pixels
//     R = 64*(o>>4) + 16*g + (o&15) => lane holds all 4 gates of 4
//     contiguous o per (pixel,fn) fragment: g = fm, o = (wm/64)*16+quad*4+r
//  4) elementwise LSTM on float4, c f32 r/w, h bf16x2 w, Wout shuffle-reduce
// ---------------------------------------------------------------------------
__global__ __launch_bounds__(256) void gate_theta_mfma(
    const float* __restrict__ Cb, const float* __restrict__ theta,
    const float* __restrict__ bias, const ushort_t* __restrict__ Wstack,
    const float* __restrict__ bfv, const float* __restrict__ biv,
    const float* __restrict__ bov, const float* __restrict__ bcv,
    const float* __restrict__ Wout, const float* __restrict__ bout,
    ushort_t* __restrict__ h0, ushort_t* __restrict__ h1g,
    float* __restrict__ c, float* __restrict__ x, int first)
{
    __shared__ __align__(16) ushort_t sB0[128 * 72];  // [px][k] hi, pad 72
    __shared__ __align__(16) ushort_t sB1[128 * 72];  // lo
    __shared__ float sth[800];
    __shared__ float sbias[32];
    __shared__ float red[256];                        // [px][wm-half]

    const int tid = threadIdx.x;
    const int lane = tid & 63, w4 = tid >> 6;
    const int wm = (w4 & 1) * 64, wn = (w4 >> 1) * 64;
    const int lm = lane & 15, quad = lane >> 4;
    const int m = blockIdx.x / 6;
    const int n0 = (blockIdx.x % 6) * 128;
    const int pbase = m * DIM + n0;

    // A-fragments (weights) straight from global (L2-resident, 16 KB total)
    bf16x8 af[4][2];
#pragma unroll
    for (int fm = 0; fm < 4; ++fm)
#pragma unroll
        for (int kc = 0; kc < 2; ++kc)
            af[fm][kc] = *(const bf16x8*)&Wstack[(wm + fm * 16 + lm) * 64 +
                                                 kc * 32 + quad * 8];

    for (int t = tid; t < 800; t += 256) sth[t] = theta[t];
    if (tid < 32) sbias[tid] = bias[tid];

    // stage h -> sB[px][32..63] (bf16x2) or zeros
#pragma unroll
    for (int cc = 0; cc < 4; ++cc) {
        int idx = cc * 256 + tid;            // 0..1023
        int px = idx >> 3, q = idx & 7;
        int level = q >> 2, qq = q & 3;
        uint4 v;
        if (first) {
            v.x = v.y = v.z = v.w = 0u;
        } else {
            const ushort_t* src = level ? h1g : h0;
            v = *(const uint4*)&src[(size_t)(pbase + px) * 32 + qq * 8];
        }
        ushort_t* dst = level ? sB1 : sB0;
        *(uint4*)&dst[px * 72 + 32 + qq * 8] = v;
    }
    __syncthreads();   // sth/sbias ready

    // theta contraction -> xc bf16x2 -> sB[px][0..31]
    {
        int px = tid & 127;
        int oh = (tid >> 7) * 16;
        const float* crow = Cb + (size_t)m * 3840 + n0 + px;
        float vv[16];
#pragma unroll
        for (int t = 0; t < 16; ++t) vv[t] = sbias[oh + t];
#pragma unroll
        for (int i = 0; i < 5; ++i)
#pragma unroll
            for (int j = 0; j < 5; ++j) {
                float cv = crow[(size_t)(i * DIM) * 3840 + j * DIM];
                const float* th = &sth[(i * 5 + j) * 32 + oh];
#pragma unroll
                for (int t = 0; t < 16; ++t) vv[t] = fmaf(cv, th[t], vv[t]);
            }
        unsigned hw[8], lw[8];
#pragma unroll
        for (int t = 0; t < 8; ++t) {
            unsigned short a0 = f2bf(vv[2 * t]);
            unsigned short a1 = f2bf(vv[2 * t + 1]);
            unsigned short b0 = f2bf(vv[2 * t] - bf2f(a0));
            unsigned short b1 = f2bf(vv[2 * t + 1] - bf2f(a1));
            hw[t] = (unsigned)a0 | ((unsigned)a1 << 16);
            lw[t] = (unsigned)b0 | ((unsigned)b1 << 16);
        }
        uint4* d0 = (uint4*)&sB0[px * 72 + oh];
        uint4* d1 = (uint4*)&sB1[px * 72 + oh];
        d0[0] = make_uint4(hw[0], hw[1], hw[2], hw[3]);
        d0[1] = make_uint4(hw[4], hw[5], hw[6], hw[7]);
        d1[0] = make_uint4(lw[0], lw[1], lw[2], lw[3]);
        d1[1] = make_uint4(lw[4], lw[5], lw[6], lw[7]);
    }
    __syncthreads();

    // MFMA: acc[g][fn] over K=64 (2 chunks), B = hi+lo
    f32x4 acc[4][4] = {};
#pragma unroll
    for (int kc = 0; kc < 2; ++kc) {
        bf16x8 bh[4], bl[4];
#pragma unroll
        for (int fn = 0; fn < 4; ++fn) {
            int br = (wn + fn * 16 + lm) * 72 + kc * 32 + quad * 8;
            bh[fn] = *(const bf16x8*)&sB0[br];
            bl[fn] = *(const bf16x8*)&sB1[br];
        }
#pragma unroll
        for (int fm = 0; fm < 4; ++fm)
#pragma unroll
            for (int fn = 0; fn < 4; ++fn) {
                f32x4 a = acc[fm][fn];
                a = __builtin_amdgcn_mfma_f32_16x16x32_bf16(af[fm][kc], bl[fn], a, 0, 0, 0);
                a = __builtin_amdgcn_mfma_f32_16x16x32_bf16(af[fm][kc], bh[fn], a, 0, 0, 0);
                acc[fm][fn] = a;
            }
    }

    // epilogue: lane holds gates g=fm for o = o0..o0+3, pixel = wn+fn*16+lm
    const int o0 = (wm >> 2) + quad * 4;            // (wm/64)*16 + quad*4
    const float4 bgf = *(const float4*)&bfv[o0];
    const float4 bgi = *(const float4*)&biv[o0];
    const float4 bgo = *(const float4*)&bov[o0];
    const float4 bgc = *(const float4*)&bcv[o0];
    const float4 wo4 = *(const float4*)&Wout[o0];

#pragma unroll
    for (int fn = 0; fn < 4; ++fn) {
        int px = wn + fn * 16 + lm;
        size_t p = (size_t)(pbase + px);
        float4 cold;
        if (first) { cold.x = cold.y = cold.z = cold.w = 0.f; }
        else cold = *(const float4*)&c[p * 32 + o0];
        float co[4] = {cold.x, cold.y, cold.z, cold.w};
        float bf4[4] = {bgf.x, bgf.y, bgf.z, bgf.w};
        float bi4[4] = {bgi.x, bgi.y, bgi.z, bgi.w};
        float bo4[4] = {bgo.x, bgo.y, bgo.z, bgo.w};
        float bc4[4] = {bgc.x, bgc.y, bgc.z, bgc.w};
        float wo[4] = {wo4.x, wo4.y, wo4.z, wo4.w};
        float cn[4], hn[4];
        float part = 0.f;
#pragma unroll
        for (int r = 0; r < 4; ++r) {
            float fg = sigm(acc[0][fn][r] + bf4[r]);
            float ig = sigm(acc[1][fn][r] + bi4[r]);
            float og = sigm(acc[2][fn][r] + bo4[r]);
            float gg = sigm(acc[3][fn][r] + bc4[r]);
            cn[r] = fg * co[r] + ig * gg;
            hn[r] = og * sigm(cn[r]);
            part = fmaf(cn[r], wo[r], part);
        }
        float4 cnv; cnv.x = cn[0]; cnv.y = cn[1]; cnv.z = cn[2]; cnv.w = cn[3];
        *(float4*)&c[p * 32 + o0] = cnv;
        unsigned short hh[4], hl[4];
#pragma unroll
        for (int r = 0; r < 4; ++r) {
            hh[r] = f2bf(hn[r]);
            hl[r] = f2bf(hn[r] - bf2f(hh[r]));
        }
        uint2 ph, pl;
        ph.x = (unsigned)hh[0] | ((unsigned)hh[1] << 16);
        ph.y = (unsigned)hh[2] | ((unsigned)hh[3] << 16);
        pl.x = (unsigned)hl[0] | ((unsigned)hl[1] << 16);
        pl.y = (unsigned)hl[2] | ((unsigned)hl[3] << 16);
        *(uint2*)&h0[p * 32 + o0] = ph;
        *(uint2*)&h1g[p * 32 + o0] = pl;
        // reduce over o: quad bits are lane bits 4,5
        part += __shfl_xor(part, 16, 64);
        part += __shfl_xor(part, 32, 64);
        if (quad == 0) red[px * 2 + (wm >> 6)] = part;
    }
    __syncthreads();
    if (tid < 128) {
        float v = red[tid * 2] + red[tid * 2 + 1] + bout[0];
        v = fminf(fmaxf(v, -15.f), 15.f);
        float e = __expf(2.f * v);
        x[pbase + tid] += (e - 1.f) / (e + 1.f);
    }
}

// ---------------------------------------------------------------------------
extern "C" void kernel_launch(void* const* d_in, const int* in_sizes, int n_in,
                              void* d_out, int out_size, void* d_ws, size_t ws_size,
                              hipStream_t stream)
{
    const float* x_in  = (const float*)d_in[0];
    const float* Lrow  = (const float*)d_in[1];
    const float* Lcol  = (const float*)d_in[2];
    const float* theta = (const float*)d_in[3];
    const float* bias  = (const float*)d_in[4];
    const float* Wf = (const float*)d_in[5];
    const float* Uf = (const float*)d_in[6];
    const float* bf = (const float*)d_in[7];
    const float* Wi = (const float*)d_in[8];
    const float* Ui = (const float*)d_in[9];
    const float* bi = (const float*)d_in[10];
    const float* Wo = (const float*)d_in[11];
    const float* Uo = (const float*)d_in[12];
    const float* bo = (const float*)d_in[13];
    const float* Wc = (const float*)d_in[14];
    const float* Uc = (const float*)d_in[15];
    const float* bc = (const float*)d_in[16];
    const float* Wout = (const float*)d_in[17];
    const float* bout = (const float*)d_in[18];
    (void)in_sizes; (void)n_in; (void)out_size;

    float* out = (float*)d_out;   // working x buffer

    // ---- workspace pool (263.08 MB; harness provides >= 264.2 MB) ----
    float* ws   = (float*)d_ws;
    float* Cbig = ws;                                // 14,745,600 f (59 MB)
    float* c    = ws + 14745600;                     // 18,874,368 f
    ushort_t* base2 = (ushort_t*)(c + 18874368);
    ushort_t* h0 = base2;                            // 18,874,368 sh
    ushort_t* h1 = h0 + 18874368;                    // 18,874,368 sh
    ushort_t* S0 = h1 + 18874368;                    // 10*MXK (Tr | Tc)
    ushort_t* S1 = S0 + 2 * STK;
    ushort_t* S2 = S1 + 2 * STK;
    ushort_t* XRS0 = S2 + 2 * STK;                   // 5*MXK
    ushort_t* XRS1 = XRS0 + STK;
    ushort_t* XRS2 = XRS1 + STK;
    ushort_t* Wstack = XRS2 + STK;                   // 8192 sh
    ushort_t* xTS0 = (ushort_t*)Cbig;                // per-iter alias
    ushort_t* xTS1 = xTS0 + MXK;
    ushort_t* xTS2 = xTS1 + MXK;
    if (ws_size < (size_t)263077888) return;

    hipMemcpyAsync(out, x_in, (size_t)MXK * 4, hipMemcpyDeviceToDevice, stream);

    prep_gate_weights<<<32, 256, 0, stream>>>(Wf, Wi, Wo, Wc, Uf, Ui, Uo, Uc,
                                              Wstack);
    init_split<<<MXK / 256, 256, 0, stream>>>(Lrow, Lcol, S0, S1, S2);
    // Cheb recursion, Tr+Tc batched: A = T1 (= L), dual stack via halfStride
    for (int k = 2; k <= 4; ++k) {
        gemm_bt_x3<<<72, 256, 0, stream>>>(
            S0 + MXK, S1 + MXK, S2 + MXK,
            S0 + (size_t)(k - 1) * MXK, S1 + (size_t)(k - 1) * MXK,
            S2 + (size_t)(k - 1) * MXK,
            S0 + (size_t)(k - 2) * MXK, S1 + (size_t)(k - 2) * MXK,
            S2 + (size_t)(k - 2) * MXK,
            nullptr,
            S0 + (size_t)k * MXK, S1 + (size_t)k * MXK, S2 + (size_t)k * MXK,
            DIM, DIM, 2, 6, STK);
    }

    for (int it = 0; it < 3; ++it) {
        transpose_cvt3<<<dim3(24, 24), 256, 0, stream>>>(out, xTS0, xTS1, xTS2);
        // stage1: XRv = TrV @ x  (M=3840, N=768, K=768), bf16x3 out
        gemm_bt_x3<<<180, 256, 0, stream>>>(
            S0, S1, S2, xTS0, xTS1, xTS2,
            nullptr, nullptr, nullptr,
            nullptr, XRS0, XRS1, XRS2, DIM, DIM, 1, 6, 0);
        // stage2: C_big = XRv @ TcV^T  (M=3840, N=3840, K=768), fp32 out
        gemm_bt_x3<<<900, 256, 0, stream>>>(
            XRS0, XRS1, XRS2, S0 + STK, S1 + STK, S2 + STK,
            nullptr, nullptr, nullptr,
            Cbig, nullptr, nullptr, nullptr, DIM, 3840, 0, 30, 0);
        // gates: theta contraction + MFMA + LSTM + x += tanh(c.Wout+b)
        gate_theta_mfma<<<4608, 256, 0, stream>>>(
            Cbig, theta, bias, Wstack,
            bf, bi, bo, bc, Wout, bout, h0, h1, c, out, it == 0 ? 1 : 0);
    }
}

// Round 6
// 1141.052 us; speedup vs baseline: 4.6767x; 1.0147x over previous
//
#include <hip/hip_runtime.h>
#include <hip/hip_bf16.h>
#include <stdint.h>

// ---------------------------------------------------------------------------
// MGCNN on MI355X — scaled-f16x2 MFMA conv + bf16 MFMA gate kernel.
//
// f16x2s number format: a = a1 + a2*2^-11,  a1 = f16(a), a2 = f16((a-a1)*2^11)
//   (residual pre-scaled by 2^11 so it stays f16-NORMAL; avoids denorm flush)
// GEMM: acc1 = sum a1b1 ; acc2 = sum (a1b2 + a2b1) ; D = acc1 + acc2*2^-11
//   -> 3 MFMAs per K-chunk vs bf16x3's 6; error ~2^-21 (fp32-grade here).
//
//   S_l levels hold Tr stack (rows 0..3839) then Tc stack (+STK).
//   cheb  :  T_k = 2*(L @ T_{k-1}) - T_{k-2}          (mode 2, both stacks)
//   stage1:  XRv[(i,m)][q] = sum_p T_i[m][p]*xT[q][p]  (mode 1, f16x2s out)
//   stage2:  C_big[(i,m)][(j,n)] = sum_q XRv*TcV       (mode 0, fp32 out)
//   gate  :  theta-contract C_big -> xc(LDS bf16x2) -> MFMA vs weight stack
//            -> LSTM elementwise in-register -> c(f32), h(bf16x2), x += dx
// ---------------------------------------------------------------------------

#define DIM 768
#define MXK 589824        // 768*768
#define STK 2949120       // 5*768*768
#define RSCALE 2048.0f
#define RINV   (1.0f / 2048.0f)

typedef _Float16 f16x8 __attribute__((ext_vector_type(8)));
typedef short bf16x8 __attribute__((ext_vector_type(8)));
typedef float f32x4 __attribute__((ext_vector_type(4)));
typedef unsigned short ushort_t;
typedef _Float16 f16_t;

__device__ __forceinline__ float sigm(float v) {
    return 1.0f / (1.0f + __expf(-v));
}
__device__ __forceinline__ unsigned short f2bf(float f) {
    unsigned u = __float_as_uint(f);
    return (unsigned short)((u + 0x7FFF + ((u >> 16) & 1)) >> 16);
}
__device__ __forceinline__ float bf2f(unsigned short b) {
    return __uint_as_float(((unsigned)b) << 16);
}
__device__ __forceinline__ void split2h(float f, f16_t& h1, f16_t& h2) {
    h1 = (f16_t)f;
    float r = f - (float)h1;
    h2 = (f16_t)(r * RSCALE);
}

// async 16B global->LDS (LDS dest = wave-uniform base + lane*16)
__device__ __forceinline__ void gl_lds16(const f16_t* g, f16_t* l) {
    auto gp = reinterpret_cast<const __attribute__((address_space(1))) uint32_t*>(
        reinterpret_cast<uintptr_t>(g));
    auto lp = reinterpret_cast<__attribute__((address_space(3))) uint32_t*>(
        reinterpret_cast<uintptr_t>(l));
    __builtin_amdgcn_global_load_lds(gp, lp, 16, 0, 0);
}

// ---------------------------------------------------------------------------
// init: T0 = I, T1 = L  ->  f16x2s, Tr stack then Tc stack per level
// ---------------------------------------------------------------------------
__global__ __launch_bounds__(256) void init_split(
    const float* __restrict__ Lrow, const float* __restrict__ Lcol,
    f16_t* __restrict__ S0, f16_t* __restrict__ S1)
{
    int idx = blockIdx.x * 256 + threadIdx.x;      // 0 .. 768*768-1
    int p = idx / DIM, m = idx % DIM;
    f16_t eye = (p == m) ? (f16_t)1.0f : (f16_t)0.0f;
    S0[idx] = eye; S1[idx] = (f16_t)0.0f;                    // Tr T0
    S0[STK + idx] = eye; S1[STK + idx] = (f16_t)0.0f;        // Tc T0
    f16_t h1, h2;
    split2h(Lrow[idx], h1, h2);
    S0[MXK + idx] = h1; S1[MXK + idx] = h2;
    split2h(Lcol[idx], h1, h2);
    S0[STK + MXK + idx] = h1; S1[STK + MXK + idx] = h2;
}

// ---------------------------------------------------------------------------
// weight stack prep: Wstack[R][k] bf16, R in 0..127, k in 0..63
//   g = (R>>4)&3 (gate f,i,o,c), o = (R>>6)*16 + (R&15)
// ---------------------------------------------------------------------------
__global__ __launch_bounds__(256) void prep_gate_weights(
    const float* __restrict__ Wf, const float* __restrict__ Wi,
    const float* __restrict__ Wo, const float* __restrict__ Wc,
    const float* __restrict__ Uf, const float* __restrict__ Ui,
    const float* __restrict__ Uo, const float* __restrict__ Uc,
    ushort_t* __restrict__ Wstack)
{
    int idx = blockIdx.x * 256 + threadIdx.x;
    if (idx >= 8192) return;
    int R = idx >> 6, k = idx & 63;
    int g = (R >> 4) & 3, o = (R >> 6) * 16 + (R & 15);
    const float* Wg[4] = {Wf, Wi, Wo, Wc};
    const float* Ug[4] = {Uf, Ui, Uo, Uc};
    float v = (k < 32) ? Wg[g][k * 32 + o] : Ug[g][(k - 32) * 32 + o];
    Wstack[idx] = f2bf(v);
}

// ---------------------------------------------------------------------------
// transpose 768x768 + f16x2s split:  xT[q][p] = x[p][q]
// ---------------------------------------------------------------------------
__global__ __launch_bounds__(256) void transpose_cvt2(
    const float* __restrict__ in, f16_t* __restrict__ o1,
    f16_t* __restrict__ o2)
{
    __shared__ float t[32][33];
    int x = threadIdx.x & 31, y = threadIdx.x >> 5;
    int bx = blockIdx.x * 32, by = blockIdx.y * 32;
#pragma unroll
    for (int r = 0; r < 4; ++r)
        t[y + 8 * r][x] = in[(size_t)(by + y + 8 * r) * DIM + bx + x];
    __syncthreads();
#pragma unroll
    for (int r = 0; r < 4; ++r) {
        float v = t[x][y + 8 * r];
        f16_t h1, h2;
        split2h(v, h1, h2);
        size_t o = (size_t)(bx + y + 8 * r) * DIM + by + x;
        o1[o] = h1; o2[o] = h2;
    }
}

// ---------------------------------------------------------------------------
// f16x2s MFMA GEMM engine (B-transposed, k-contig), 128x128 tile, BK=32.
// LDS chunk swizzle s(r) = (r>>1)&3 -> 2-way (free) ds_read_b128 banks.
// mode 0: C fp32, supertile grid; mode 1: f16x2s out; mode 2: cheb
// (v = 2*acc - P reconstructed), dual stack via halfStride.
// ---------------------------------------------------------------------------
__global__ __launch_bounds__(256) void gemm_bt_h2(
    const f16_t* __restrict__ A1, const f16_t* __restrict__ A2,
    const f16_t* __restrict__ B1, const f16_t* __restrict__ B2,
    const f16_t* __restrict__ P1, const f16_t* __restrict__ P2,
    float* __restrict__ C,
    f16_t* __restrict__ D1, f16_t* __restrict__ D2,
    int K, int ldc, int mode, int nbx, int halfStride)
{
    __shared__ __align__(16) f16_t sA[2][128 * 32];
    __shared__ __align__(16) f16_t sB[2][128 * 32];

    const int tid = threadIdx.x;

    int bx, by;
    size_t hoff = 0;
    if (mode == 0) {
        int g = blockIdx.x;
        int sup = g / 240;
        int rows0 = sup * 8;
        int H = 30 - rows0; if (H > 8) H = 8;
        int local = g - rows0 * 30;
        by = rows0 + local % H;
        bx = local / H;
    } else {
        bx = blockIdx.x % nbx;
        by = blockIdx.x / nbx;
        if (mode == 2 && by >= 6) { by -= 6; hoff = (size_t)halfStride; }
    }
    const int m0 = by * 128, n0 = bx * 128;

    const int lane = tid & 63, w4 = tid >> 6;
    const int wm = (w4 & 1) * 64, wn = (w4 >> 1) * 64;
    const int lm = lane & 15, quad = lane >> 4;
    const int psw = (quad ^ ((lm >> 1) & 3)) * 8;   // swizzled chunk (f16)

    const int L0 = w4 * 128 + lane, L1 = L0 + 64;
    const int r0 = L0 >> 2, c0 = (L0 & 3) ^ ((r0 >> 1) & 3);
    const int r1 = L1 >> 2, c1 = (L1 & 3) ^ ((r1 >> 1) & 3);

    const f16_t* gA[2][2];
    const f16_t* gB[2][2];
    const f16_t* Asrc[2] = {A1 + hoff, A2 + hoff};
    const f16_t* Bsrc[2] = {B1 + hoff, B2 + hoff};
#pragma unroll
    for (int l = 0; l < 2; ++l) {
        gA[l][0] = Asrc[l] + (size_t)(m0 + r0) * K + c0 * 8;
        gA[l][1] = Asrc[l] + (size_t)(m0 + r1) * K + c1 * 8;
        gB[l][0] = Bsrc[l] + (size_t)(n0 + r0) * K + c0 * 8;
        gB[l][1] = Bsrc[l] + (size_t)(n0 + r1) * K + c1 * 8;
    }
    f16_t* dA[2][2];
    f16_t* dB[2][2];
#pragma unroll
    for (int l = 0; l < 2; ++l) {
        dA[l][0] = &sA[l][w4 * 1024];
        dA[l][1] = &sA[l][w4 * 1024 + 512];
        dB[l][0] = &sB[l][w4 * 1024];
        dB[l][1] = &sB[l][w4 * 1024 + 512];
    }

    f32x4 acc1[4][4] = {};
    f32x4 acc2[4][4] = {};

    for (int kb = 0; kb < K; kb += 32) {
#pragma unroll
        for (int l = 0; l < 2; ++l) {
            gl_lds16(gA[l][0] + kb, dA[l][0]);
            gl_lds16(gA[l][1] + kb, dA[l][1]);
            gl_lds16(gB[l][0] + kb, dB[l][0]);
            gl_lds16(gB[l][1] + kb, dB[l][1]);
        }
        __syncthreads();

        f16x8 bfr[2][4];
#pragma unroll
        for (int l = 0; l < 2; ++l)
#pragma unroll
            for (int fn = 0; fn < 4; ++fn)
                bfr[l][fn] = *(const f16x8*)&sB[l][(wn + fn * 16 + lm) * 32 + psw];
#pragma unroll
        for (int fm = 0; fm < 4; ++fm) {
            const int ar = (wm + fm * 16 + lm) * 32 + psw;
            f16x8 a1 = *(const f16x8*)&sA[0][ar];
            f16x8 a2 = *(const f16x8*)&sA[1][ar];
#pragma unroll
            for (int fn = 0; fn < 4; ++fn) {
                acc2[fm][fn] = __builtin_amdgcn_mfma_f32_16x16x32_f16(
                    a2, bfr[0][fn], acc2[fm][fn], 0, 0, 0);
                acc2[fm][fn] = __builtin_amdgcn_mfma_f32_16x16x32_f16(
                    a1, bfr[1][fn], acc2[fm][fn], 0, 0, 0);
                acc1[fm][fn] = __builtin_amdgcn_mfma_f32_16x16x32_f16(
                    a1, bfr[0][fn], acc1[fm][fn], 0, 0, 0);
            }
        }
        __syncthreads();
    }

    // epilogue: C/D layout col=lane&15, row=quad*4+reg  [verified m89/m91]
#pragma unroll
    for (int fm = 0; fm < 4; ++fm)
#pragma unroll
        for (int fn = 0; fn < 4; ++fn) {
            int col = n0 + wn + fn * 16 + lm;
#pragma unroll
            for (int r = 0; r < 4; ++r) {
                int row = m0 + wm + fm * 16 + quad * 4 + r;
                size_t o = (size_t)row * ldc + col;
                float val = acc1[fm][fn][r] + acc2[fm][fn][r] * RINV;
                if (mode == 0) {
                    C[o] = val;
                } else {
                    if (mode == 2)
                        val = 2.0f * val -
                              ((float)P1[hoff + o] + (float)P2[hoff + o] * RINV);
                    f16_t h1, h2;
                    split2h(val, h1, h2);
                    D1[hoff + o] = h1; D2[hoff + o] = h2;
                }
            }
        }
}

// ---------------------------------------------------------------------------
// MFMA gate kernel (unchanged from R5). Block = 128 pixels.
// ---------------------------------------------------------------------------
__global__ __launch_bounds__(256) void gate_theta_mfma(
    const float* __restrict__ Cb, const float* __restrict__ theta,
    const float* __restrict__ bias, const ushort_t* __restrict__ Wstack,
    const float* __restrict__ bfv, const float* __restrict__ biv,
    const float* __restrict__ bov, const float* __restrict__ bcv,
    const float* __restrict__ Wout, const float* __restrict__ bout,
    ushort_t* __restrict__ h0, ushort_t* __restrict__ h1g,
    float* __restrict__ c, float* __restrict__ x, int first)
{
    __shared__ __align__(16) ushort_t sB0[128 * 72];
    __shared__ __align__(16) ushort_t sB1[128 * 72];
    __shared__ float sth[800];
    __shared__ float sbias[32];
    __shared__ float red[256];

    const int tid = threadIdx.x;
    const int lane = tid & 63, w4 = tid >> 6;
    const int wm = (w4 & 1) * 64, wn = (w4 >> 1) * 64;
    const int lm = lane & 15, quad = lane >> 4;
    const int m = blockIdx.x / 6;
    const int n0 = (blockIdx.x % 6) * 128;
    const int pbase = m * DIM + n0;

    bf16x8 af[4][2];
#pragma unroll
    for (int fm = 0; fm < 4; ++fm)
#pragma unroll
        for (int kc = 0; kc < 2; ++kc)
            af[fm][kc] = *(const bf16x8*)&Wstack[(wm + fm * 16 + lm) * 64 +
                                                 kc * 32 + quad * 8];

    for (int t = tid; t < 800; t += 256) sth[t] = theta[t];
    if (tid < 32) sbias[tid] = bias[tid];

#pragma unroll
    for (int cc = 0; cc < 4; ++cc) {
        int idx = cc * 256 + tid;
        int px = idx >> 3, q = idx & 7;
        int level = q >> 2, qq = q & 3;
        uint4 v;
        if (first) {
            v.x = v.y = v.z = v.w = 0u;
        } else {
            const ushort_t* src = level ? h1g : h0;
            v = *(const uint4*)&src[(size_t)(pbase + px) * 32 + qq * 8];
        }
        ushort_t* dst = level ? sB1 : sB0;
        *(uint4*)&dst[px * 72 + 32 + qq * 8] = v;
    }
    __syncthreads();

    {
        int px = tid & 127;
        int oh = (tid >> 7) * 16;
        const float* crow = Cb + (size_t)m * 3840 + n0 + px;
        float vv[16];
#pragma unroll
        for (int t = 0; t < 16; ++t) vv[t] = sbias[oh + t];
#pragma unroll
        for (int i = 0; i < 5; ++i)
#pragma unroll
            for (int j = 0; j < 5; ++j) {
                float cv = crow[(size_t)(i * DIM) * 3840 + j * DIM];
                const float* th = &sth[(i * 5 + j) * 32 + oh];
#pragma unroll
                for (int t = 0; t < 16; ++t) vv[t] = fmaf(cv, th[t], vv[t]);
            }
        unsigned hw[8], lw[8];
#pragma unroll
        for (int t = 0; t < 8; ++t) {
            unsigned short a0 = f2bf(vv[2 * t]);
            unsigned short a1 = f2bf(vv[2 * t + 1]);
            unsigned short b0 = f2bf(vv[2 * t] - bf2f(a0));
            unsigned short b1 = f2bf(vv[2 * t + 1] - bf2f(a1));
            hw[t] = (unsigned)a0 | ((unsigned)a1 << 16);
            lw[t] = (unsigned)b0 | ((unsigned)b1 << 16);
        }
        uint4* d0 = (uint4*)&sB0[px * 72 + oh];
        uint4* d1 = (uint4*)&sB1[px * 72 + oh];
        d0[0] = make_uint4(hw[0], hw[1], hw[2], hw[3]);
        d0[1] = make_uint4(hw[4], hw[5], hw[6], hw[7]);
        d1[0] = make_uint4(lw[0], lw[1], lw[2], lw[3]);
        d1[1] = make_uint4(lw[4], lw[5], lw[6], lw[7]);
    }
    __syncthreads();

    f32x4 acc[4][4] = {};
#pragma unroll
    for (int kc = 0; kc < 2; ++kc) {
        bf16x8 bh[4], bl[4];
#pragma unroll
        for (int fn = 0; fn < 4; ++fn) {
            int br = (wn + fn * 16 + lm) * 72 + kc * 32 + quad * 8;
            bh[fn] = *(const bf16x8*)&sB0[br];
            bl[fn] = *(const bf16x8*)&sB1[br];
        }
#pragma unroll
        for (int fm = 0; fm < 4; ++fm)
#pragma unroll
            for (int fn = 0; fn < 4; ++fn) {
                f32x4 a = acc[fm][fn];
                a = __builtin_amdgcn_mfma_f32_16x16x32_bf16(af[fm][kc], bl[fn], a, 0, 0, 0);
                a = __builtin_amdgcn_mfma_f32_16x16x32_bf16(af[fm][kc], bh[fn], a, 0, 0, 0);
                acc[fm][fn] = a;
            }
    }

    const int o0 = (wm >> 2) + quad * 4;
    const float4 bgf = *(const float4*)&bfv[o0];
    const float4 bgi = *(const float4*)&biv[o0];
    const float4 bgo = *(const float4*)&bov[o0];
    const float4 bgc = *(const float4*)&bcv[o0];
    const float4 wo4 = *(const float4*)&Wout[o0];

#pragma unroll
    for (int fn = 0; fn < 4; ++fn) {
        int px = wn + fn * 16 + lm;
        size_t p = (size_t)(pbase + px);
        float4 cold;
        if (first) { cold.x = cold.y = cold.z = cold.w = 0.f; }
        else cold = *(const float4*)&c[p * 32 + o0];
        float co[4] = {cold.x, cold.y, cold.z, cold.w};
        float bf4[4] = {bgf.x, bgf.y, bgf.z, bgf.w};
        float bi4[4] = {bgi.x, bgi.y, bgi.z, bgi.w};
        float bo4[4] = {bgo.x, bgo.y, bgo.z, bgo.w};
        float bc4[4] = {bgc.x, bgc.y, bgc.z, bgc.w};
        float wo[4] = {wo4.x, wo4.y, wo4.z, wo4.w};
        float cn[4], hn[4];
        float part = 0.f;
#pragma unroll
        for (int r = 0; r < 4; ++r) {
            float fg = sigm(acc[0][fn][r] + bf4[r]);
            float ig = sigm(acc[1][fn][r] + bi4[r]);
            float og = sigm(acc[2][fn][r] + bo4[r]);
            float gg = sigm(acc[3][fn][r] + bc4[r]);
            cn[r] = fg * co[r] + ig * gg;
            hn[r] = og * sigm(cn[r]);
            part = fmaf(cn[r], wo[r], part);
        }
        float4 cnv; cnv.x = cn[0]; cnv.y = cn[1]; cnv.z = cn[2]; cnv.w = cn[3];
        *(float4*)&c[p * 32 + o0] = cnv;
        unsigned short hh[4], hl[4];
#pragma unroll
        for (int r = 0; r < 4; ++r) {
            hh[r] = f2bf(hn[r]);
            hl[r] = f2bf(hn[r] - bf2f(hh[r]));
        }
        uint2 ph, pl;
        ph.x = (unsigned)hh[0] | ((unsigned)hh[1] << 16);
        ph.y = (unsigned)hh[2] | ((unsigned)hh[3] << 16);
        pl.x = (unsigned)hl[0] | ((unsigned)hl[1] << 16);
        pl.y = (unsigned)hl[2] | ((unsigned)hl[3] << 16);
        *(uint2*)&h0[p * 32 + o0] = ph;
        *(uint2*)&h1g[p * 32 + o0] = pl;
        part += __shfl_xor(part, 16, 64);
        part += __shfl_xor(part, 32, 64);
        if (quad == 0) red[px * 2 + (wm >> 6)] = part;
    }
    __syncthreads();
    if (tid < 128) {
        float v = red[tid * 2] + red[tid * 2 + 1] + bout[0];
        v = fminf(fmaxf(v, -15.f), 15.f);
        float e = __expf(2.f * v);
        x[pbase + tid] += (e - 1.f) / (e + 1.f);
    }
}

// ---------------------------------------------------------------------------
extern "C" void kernel_launch(void* const* d_in, const int* in_sizes, int n_in,
                              void* d_out, int out_size, void* d_ws, size_t ws_size,
                              hipStream_t stream)
{
    const float* x_in  = (const float*)d_in[0];
    const float* Lrow  = (const float*)d_in[1];
    const float* Lcol  = (const float*)d_in[2];
    const float* theta = (const float*)d_in[3];
    const float* bias  = (const float*)d_in[4];
    const float* Wf = (const float*)d_in[5];
    const float* Uf = (const float*)d_in[6];
    const float* bf = (const float*)d_in[7];
    const float* Wi = (const float*)d_in[8];
    const float* Ui = (const float*)d_in[9];
    const float* bi = (const float*)d_in[10];
    const float* Wo = (const float*)d_in[11];
    const float* Uo = (const float*)d_in[12];
    const float* bo = (const float*)d_in[13];
    const float* Wc = (const float*)d_in[14];
    const float* Uc = (const float*)d_in[15];
    const float* bc = (const float*)d_in[16];
    const float* Wout = (const float*)d_in[17];
    const float* bout = (const float*)d_in[18];
    (void)in_sizes; (void)n_in; (void)out_size;

    float* out = (float*)d_out;   // working x buffer

    // ---- workspace pool (245.4 MB; harness provides >= 263 MB proven) ----
    float* ws   = (float*)d_ws;
    float* Cbig = ws;                                // 14,745,600 f (59 MB)
    float* c    = ws + 14745600;                     // 18,874,368 f
    ushort_t* h0 = (ushort_t*)(c + 18874368);        // 18,874,368 sh
    ushort_t* h1 = h0 + 18874368;                    // 18,874,368 sh
    f16_t* S0 = (f16_t*)(h1 + 18874368);             // 2*STK (Tr | Tc)
    f16_t* S1 = S0 + 2 * STK;
    f16_t* XR0 = S1 + 2 * STK;                       // STK
    f16_t* XR1 = XR0 + STK;
    ushort_t* Wstack = (ushort_t*)(XR1 + STK);       // 8192 sh
    f16_t* xT0 = (f16_t*)Cbig;                       // per-iter alias
    f16_t* xT1 = xT0 + MXK;
    if (ws_size < (size_t)245383168) return;

    hipMemcpyAsync(out, x_in, (size_t)MXK * 4, hipMemcpyDeviceToDevice, stream);

    prep_gate_weights<<<32, 256, 0, stream>>>(Wf, Wi, Wo, Wc, Uf, Ui, Uo, Uc,
                                              Wstack);
    init_split<<<MXK / 256, 256, 0, stream>>>(Lrow, Lcol, S0, S1);
    // Cheb recursion, Tr+Tc batched: A = T1 (= L), dual stack via halfStride
    for (int k = 2; k <= 4; ++k) {
        gemm_bt_h2<<<72, 256, 0, stream>>>(
            S0 + MXK, S1 + MXK,
            S0 + (size_t)(k - 1) * MXK, S1 + (size_t)(k - 1) * MXK,
            S0 + (size_t)(k - 2) * MXK, S1 + (size_t)(k - 2) * MXK,
            nullptr,
            S0 + (size_t)k * MXK, S1 + (size_t)k * MXK,
            DIM, DIM, 2, 6, STK);
    }

    for (int it = 0; it < 3; ++it) {
        transpose_cvt2<<<dim3(24, 24), 256, 0, stream>>>(out, xT0, xT1);
        // stage1: XRv = TrV @ x  (M=3840, N=768, K=768), f16x2s out
        gemm_bt_h2<<<180, 256, 0, stream>>>(
            S0, S1, xT0, xT1,
            nullptr, nullptr,
            nullptr, XR0, XR1, DIM, DIM, 1, 6, 0);
        // stage2: C_big = XRv @ TcV^T  (M=3840, N=3840, K=768), fp32 out
        gemm_bt_h2<<<900, 256, 0, stream>>>(
            XR0, XR1, S0 + STK, S1 + STK,
            nullptr, nullptr,
            Cbig, nullptr, nullptr, DIM, 3840, 0, 30, 0);
        // gates: theta contraction + MFMA + LSTM + x += tanh(c.Wout+b)
        gate_theta_mfma<<<4608, 256, 0, stream>>>(
            Cbig, theta, bias, Wstack,
            bf, bi, bo, bc, Wout, bout, h0, h1, c, out, it == 0 ? 1 : 0);
    }
}

// Round 7
// 933.057 us; speedup vs baseline: 5.7192x; 1.2229x over previous
//
#include <hip/hip_runtime.h>
#include <hip/hip_bf16.h>
#include <stdint.h>

// ---------------------------------------------------------------------------
// MGCNN on MI355X — scaled-f16x2 MFMA conv + bf16 MFMA gate kernel.
//
// f16x2s format: a = a1 + a2*2^-11, a1 = f16(a), a2 = f16((a-a1)*2^11)
// GEMM: acc1 = sum a1b1 ; acc2 = sum (a1b2 + a2b1) ; D = acc1 + acc2*2^-11
//
// R7: block tile 128x64, wave tile 64x32 -> dual acc = 64 VGPRs (R6's
// 64x64/wave needed 128 acc VGPRs -> occupancy cliff at vgpr=128 [m69],
// blocks/CU 3->2, MfmaUtil 43->17%). Smaller tile restores 4 waves/SIMD.
// ---------------------------------------------------------------------------

#define DIM 768
#define MXK 589824        // 768*768
#define STK 2949120       // 5*768*768
#define RSCALE 2048.0f
#define RINV   (1.0f / 2048.0f)

typedef _Float16 f16x8 __attribute__((ext_vector_type(8)));
typedef short bf16x8 __attribute__((ext_vector_type(8)));
typedef float f32x4 __attribute__((ext_vector_type(4)));
typedef unsigned short ushort_t;
typedef _Float16 f16_t;

__device__ __forceinline__ float sigm(float v) {
    return 1.0f / (1.0f + __expf(-v));
}
__device__ __forceinline__ unsigned short f2bf(float f) {
    unsigned u = __float_as_uint(f);
    return (unsigned short)((u + 0x7FFF + ((u >> 16) & 1)) >> 16);
}
__device__ __forceinline__ float bf2f(unsigned short b) {
    return __uint_as_float(((unsigned)b) << 16);
}
__device__ __forceinline__ void split2h(float f, f16_t& h1, f16_t& h2) {
    h1 = (f16_t)f;
    float r = f - (float)h1;
    h2 = (f16_t)(r * RSCALE);
}

// async 16B global->LDS (LDS dest = wave-uniform base + lane*16)
__device__ __forceinline__ void gl_lds16(const f16_t* g, f16_t* l) {
    auto gp = reinterpret_cast<const __attribute__((address_space(1))) uint32_t*>(
        reinterpret_cast<uintptr_t>(g));
    auto lp = reinterpret_cast<__attribute__((address_space(3))) uint32_t*>(
        reinterpret_cast<uintptr_t>(l));
    __builtin_amdgcn_global_load_lds(gp, lp, 16, 0, 0);
}

// ---------------------------------------------------------------------------
// init: T0 = I, T1 = L  ->  f16x2s, Tr stack then Tc stack per level
// ---------------------------------------------------------------------------
__global__ __launch_bounds__(256) void init_split(
    const float* __restrict__ Lrow, const float* __restrict__ Lcol,
    f16_t* __restrict__ S0, f16_t* __restrict__ S1)
{
    int idx = blockIdx.x * 256 + threadIdx.x;      // 0 .. 768*768-1
    int p = idx / DIM, m = idx % DIM;
    f16_t eye = (p == m) ? (f16_t)1.0f : (f16_t)0.0f;
    S0[idx] = eye; S1[idx] = (f16_t)0.0f;                    // Tr T0
    S0[STK + idx] = eye; S1[STK + idx] = (f16_t)0.0f;        // Tc T0
    f16_t h1, h2;
    split2h(Lrow[idx], h1, h2);
    S0[MXK + idx] = h1; S1[MXK + idx] = h2;
    split2h(Lcol[idx], h1, h2);
    S0[STK + MXK + idx] = h1; S1[STK + MXK + idx] = h2;
}

// ---------------------------------------------------------------------------
// weight stack prep: Wstack[R][k] bf16, R in 0..127, k in 0..63
// ---------------------------------------------------------------------------
__global__ __launch_bounds__(256) void prep_gate_weights(
    const float* __restrict__ Wf, const float* __restrict__ Wi,
    const float* __restrict__ Wo, const float* __restrict__ Wc,
    const float* __restrict__ Uf, const float* __restrict__ Ui,
    const float* __restrict__ Uo, const float* __restrict__ Uc,
    ushort_t* __restrict__ Wstack)
{
    int idx = blockIdx.x * 256 + threadIdx.x;
    if (idx >= 8192) return;
    int R = idx >> 6, k = idx & 63;
    int g = (R >> 4) & 3, o = (R >> 6) * 16 + (R & 15);
    const float* Wg[4] = {Wf, Wi, Wo, Wc};
    const float* Ug[4] = {Uf, Ui, Uo, Uc};
    float v = (k < 32) ? Wg[g][k * 32 + o] : Ug[g][(k - 32) * 32 + o];
    Wstack[idx] = f2bf(v);
}

// ---------------------------------------------------------------------------
// transpose 768x768 + f16x2s split:  xT[q][p] = x[p][q]
// ---------------------------------------------------------------------------
__global__ __launch_bounds__(256) void transpose_cvt2(
    const float* __restrict__ in, f16_t* __restrict__ o1,
    f16_t* __restrict__ o2)
{
    __shared__ float t[32][33];
    int x = threadIdx.x & 31, y = threadIdx.x >> 5;
    int bx = blockIdx.x * 32, by = blockIdx.y * 32;
#pragma unroll
    for (int r = 0; r < 4; ++r)
        t[y + 8 * r][x] = in[(size_t)(by + y + 8 * r) * DIM + bx + x];
    __syncthreads();
#pragma unroll
    for (int r = 0; r < 4; ++r) {
        float v = t[x][y + 8 * r];
        f16_t h1, h2;
        split2h(v, h1, h2);
        size_t o = (size_t)(bx + y + 8 * r) * DIM + by + x;
        o1[o] = h1; o2[o] = h2;
    }
}

// ---------------------------------------------------------------------------
// f16x2s MFMA GEMM engine (B-transposed, k-contig), 128x64 tile, BK=32.
// 4 waves, wave tile 64x32 (4x2 16x16x32 frags, dual acc = 64 VGPRs).
// LDS chunk swizzle s(r) = (r>>1)&3 -> conflict-free ds_read_b128.
// mode 0: C fp32, supertile grid (60 cols); mode 1: f16x2s out;
// mode 2: cheb (v = 2*acc - P), dual stack via halfStride (by>=6).
// ---------------------------------------------------------------------------
__global__ __launch_bounds__(256) void gemm_bt_h2(
    const f16_t* __restrict__ A1, const f16_t* __restrict__ A2,
    const f16_t* __restrict__ B1, const f16_t* __restrict__ B2,
    const f16_t* __restrict__ P1, const f16_t* __restrict__ P2,
    float* __restrict__ C,
    f16_t* __restrict__ D1, f16_t* __restrict__ D2,
    int K, int ldc, int mode, int nbx, int halfStride)
{
    __shared__ __align__(16) f16_t sA[2][128 * 32];   // 16 KB
    __shared__ __align__(16) f16_t sB[2][64 * 32];    //  8 KB

    const int tid = threadIdx.x;

    int bx, by;
    size_t hoff = 0;
    if (mode == 0) {
        // supertile: 8 rows x 60 cols; stride-H ids share bx -> L2 reuse
        int g = blockIdx.x;
        int sup = g / 480;
        int rows0 = sup * 8;
        int H = 30 - rows0; if (H > 8) H = 8;
        int local = g - rows0 * 60;
        by = rows0 + local % H;
        bx = local / H;
    } else {
        bx = blockIdx.x % nbx;
        by = blockIdx.x / nbx;
        if (mode == 2 && by >= 6) { by -= 6; hoff = (size_t)halfStride; }
    }
    const int m0 = by * 128, n0 = bx * 64;

    const int lane = tid & 63, w4 = tid >> 6;
    const int wm = (w4 & 1) * 64, wn = (w4 >> 1) * 32;
    const int lm = lane & 15, quad = lane >> 4;
    const int psw = (quad ^ ((lm >> 1) & 3)) * 8;   // swizzled chunk (f16)

    // staging: 16B slots, slot s -> row s>>2, stored pos s&3 holds source
    // chunk (s&3) ^ ((row>>1)&3).  A: 512 slots/level (8 chunks of 64),
    // B: 256 slots/level (4 chunks). Wave w: A chunks {2w, 2w+1}, B chunk w.
    const int sA0 = (w4 * 2) * 64 + lane;          // A slot, call 0
    const int sA1 = (w4 * 2 + 1) * 64 + lane;      // A slot, call 1
    const int sB0 = w4 * 64 + lane;                // B slot
    const int rA0 = sA0 >> 2, cA0 = (lane & 3) ^ ((rA0 >> 1) & 3);
    const int rA1 = sA1 >> 2, cA1 = (lane & 3) ^ ((rA1 >> 1) & 3);
    const int rB0 = sB0 >> 2, cB0 = (lane & 3) ^ ((rB0 >> 1) & 3);
    const int offA0 = rA0 * K + cA0 * 8;
    const int offA1 = rA1 * K + cA1 * 8;
    const int offB0 = rB0 * K + cB0 * 8;

    const f16_t* Ag0 = A1 + hoff + (size_t)m0 * K;
    const f16_t* Ag1 = A2 + hoff + (size_t)m0 * K;
    const f16_t* Bg0 = B1 + hoff + (size_t)n0 * K;
    const f16_t* Bg1 = B2 + hoff + (size_t)n0 * K;
    f16_t* dA00 = &sA[0][(w4 * 2) * 512];
    f16_t* dA01 = &sA[0][(w4 * 2 + 1) * 512];
    f16_t* dA10 = &sA[1][(w4 * 2) * 512];
    f16_t* dA11 = &sA[1][(w4 * 2 + 1) * 512];
    f16_t* dB0  = &sB[0][w4 * 512];
    f16_t* dB1  = &sB[1][w4 * 512];

    f32x4 acc1[4][2] = {};
    f32x4 acc2[4][2] = {};

    for (int kb = 0; kb < K; kb += 32) {
        gl_lds16(Ag0 + offA0 + kb, dA00);
        gl_lds16(Ag0 + offA1 + kb, dA01);
        gl_lds16(Ag1 + offA0 + kb, dA10);
        gl_lds16(Ag1 + offA1 + kb, dA11);
        gl_lds16(Bg0 + offB0 + kb, dB0);
        gl_lds16(Bg1 + offB0 + kb, dB1);
        __syncthreads();

        f16x8 bfr[2][2];
#pragma unroll
        for (int l = 0; l < 2; ++l)
#pragma unroll
            for (int fn = 0; fn < 2; ++fn)
                bfr[l][fn] = *(const f16x8*)&sB[l][(wn + fn * 16 + lm) * 32 + psw];
#pragma unroll
        for (int fm = 0; fm < 4; ++fm) {
            const int ar = (wm + fm * 16 + lm) * 32 + psw;
            f16x8 a1 = *(const f16x8*)&sA[0][ar];
            f16x8 a2 = *(const f16x8*)&sA[1][ar];
#pragma unroll
            for (int fn = 0; fn < 2; ++fn) {
                acc2[fm][fn] = __builtin_amdgcn_mfma_f32_16x16x32_f16(
                    a2, bfr[0][fn], acc2[fm][fn], 0, 0, 0);
                acc2[fm][fn] = __builtin_amdgcn_mfma_f32_16x16x32_f16(
                    a1, bfr[1][fn], acc2[fm][fn], 0, 0, 0);
                acc1[fm][fn] = __builtin_amdgcn_mfma_f32_16x16x32_f16(
                    a1, bfr[0][fn], acc1[fm][fn], 0, 0, 0);
            }
        }
        __syncthreads();
    }

    // epilogue: C/D layout col=lane&15, row=quad*4+reg  [verified m89/m91]
#pragma unroll
    for (int fm = 0; fm < 4; ++fm)
#pragma unroll
        for (int fn = 0; fn < 2; ++fn) {
            int col = n0 + wn + fn * 16 + lm;
#pragma unroll
            for (int r = 0; r < 4; ++r) {
                int row = m0 + wm + fm * 16 + quad * 4 + r;
                size_t o = (size_t)row * ldc + col;
                float val = acc1[fm][fn][r] + acc2[fm][fn][r] * RINV;
                if (mode == 0) {
                    C[o] = val;
                } else {
                    if (mode == 2)
                        val = 2.0f * val -
                              ((float)P1[hoff + o] + (float)P2[hoff + o] * RINV);
                    f16_t h1, h2;
                    split2h(val, h1, h2);
                    D1[hoff + o] = h1; D2[hoff + o] = h2;
                }
            }
        }
}

// ---------------------------------------------------------------------------
// MFMA gate kernel (unchanged). Block = 128 pixels.
// ---------------------------------------------------------------------------
__global__ __launch_bounds__(256) void gate_theta_mfma(
    const float* __restrict__ Cb, const float* __restrict__ theta,
    const float* __restrict__ bias, const ushort_t* __restrict__ Wstack,
    const float* __restrict__ bfv, const float* __restrict__ biv,
    const float* __restrict__ bov, const float* __restrict__ bcv,
    const float* __restrict__ Wout, const float* __restrict__ bout,
    ushort_t* __restrict__ h0, ushort_t* __restrict__ h1g,
    float* __restrict__ c, float* __restrict__ x, int first)
{
    __shared__ __align__(16) ushort_t sB0[128 * 72];
    __shared__ __align__(16) ushort_t sB1[128 * 72];
    __shared__ float sth[800];
    __shared__ float sbias[32];
    __shared__ float red[256];

    const int tid = threadIdx.x;
    const int lane = tid & 63, w4 = tid >> 6;
    const int wm = (w4 & 1) * 64, wn = (w4 >> 1) * 64;
    const int lm = lane & 15, quad = lane >> 4;
    const int m = blockIdx.x / 6;
    const int n0 = (blockIdx.x % 6) * 128;
    const int pbase = m * DIM + n0;

    bf16x8 af[4][2];
#pragma unroll
    for (int fm = 0; fm < 4; ++fm)
#pragma unroll
        for (int kc = 0; kc < 2; ++kc)
            af[fm][kc] = *(const bf16x8*)&Wstack[(wm + fm * 16 + lm) * 64 +
                                                 kc * 32 + quad * 8];

    for (int t = tid; t < 800; t += 256) sth[t] = theta[t];
    if (tid < 32) sbias[tid] = bias[tid];

#pragma unroll
    for (int cc = 0; cc < 4; ++cc) {
        int idx = cc * 256 + tid;
        int px = idx >> 3, q = idx & 7;
        int level = q >> 2, qq = q & 3;
        uint4 v;
        if (first) {
            v.x = v.y = v.z = v.w = 0u;
        } else {
            const ushort_t* src = level ? h1g : h0;
            v = *(const uint4*)&src[(size_t)(pbase + px) * 32 + qq * 8];
        }
        ushort_t* dst = level ? sB1 : sB0;
        *(uint4*)&dst[px * 72 + 32 + qq * 8] = v;
    }
    __syncthreads();

    {
        int px = tid & 127;
        int oh = (tid >> 7) * 16;
        const float* crow = Cb + (size_t)m * 3840 + n0 + px;
        float vv[16];
#pragma unroll
        for (int t = 0; t < 16; ++t) vv[t] = sbias[oh + t];
#pragma unroll
        for (int i = 0; i < 5; ++i)
#pragma unroll
            for (int j = 0; j < 5; ++j) {
                float cv = crow[(size_t)(i * DIM) * 3840 + j * DIM];
                const float* th = &sth[(i * 5 + j) * 32 + oh];
#pragma unroll
                for (int t = 0; t < 16; ++t) vv[t] = fmaf(cv, th[t], vv[t]);
            }
        unsigned hw[8], lw[8];
#pragma unroll
        for (int t = 0; t < 8; ++t) {
            unsigned short a0 = f2bf(vv[2 * t]);
            unsigned short a1 = f2bf(vv[2 * t + 1]);
            unsigned short b0 = f2bf(vv[2 * t] - bf2f(a0));
            unsigned short b1 = f2bf(vv[2 * t + 1] - bf2f(a1));
            hw[t] = (unsigned)a0 | ((unsigned)a1 << 16);
            lw[t] = (unsigned)b0 | ((unsigned)b1 << 16);
        }
        uint4* d0 = (uint4*)&sB0[px * 72 + oh];
        uint4* d1 = (uint4*)&sB1[px * 72 + oh];
        d0[0] = make_uint4(hw[0], hw[1], hw[2], hw[3]);
        d0[1] = make_uint4(hw[4], hw[5], hw[6], hw[7]);
        d1[0] = make_uint4(lw[0], lw[1], lw[2], lw[3]);
        d1[1] = make_uint4(lw[4], lw[5], lw[6], lw[7]);
    }
    __syncthreads();

    f32x4 acc[4][4] = {};
#pragma unroll
    for (int kc = 0; kc < 2; ++kc) {
        bf16x8 bh[4], bl[4];
#pragma unroll
        for (int fn = 0; fn < 4; ++fn) {
            int br = (wn + fn * 16 + lm) * 72 + kc * 32 + quad * 8;
            bh[fn] = *(const bf16x8*)&sB0[br];
            bl[fn] = *(const bf16x8*)&sB1[br];
        }
#pragma unroll
        for (int fm = 0; fm < 4; ++fm)
#pragma unroll
            for (int fn = 0; fn < 4; ++fn) {
                f32x4 a = acc[fm][fn];
                a = __builtin_amdgcn_mfma_f32_16x16x32_bf16(af[fm][kc], bl[fn], a, 0, 0, 0);
                a = __builtin_amdgcn_mfma_f32_16x16x32_bf16(af[fm][kc], bh[fn], a, 0, 0, 0);
                acc[fm][fn] = a;
            }
    }

    const int o0 = (wm >> 2) + quad * 4;
    const float4 bgf = *(const float4*)&bfv[o0];
    const float4 bgi = *(const float4*)&biv[o0];
    const float4 bgo = *(const float4*)&bov[o0];
    const float4 bgc = *(const float4*)&bcv[o0];
    const float4 wo4 = *(const float4*)&Wout[o0];

#pragma unroll
    for (int fn = 0; fn < 4; ++fn) {
        int px = wn + fn * 16 + lm;
        size_t p = (size_t)(pbase + px);
        float4 cold;
        if (first) { cold.x = cold.y = cold.z = cold.w = 0.f; }
        else cold = *(const float4*)&c[p * 32 + o0];
        float co[4] = {cold.x, cold.y, cold.z, cold.w};
        float bf4[4] = {bgf.x, bgf.y, bgf.z, bgf.w};
        float bi4[4] = {bgi.x, bgi.y, bgi.z, bgi.w};
        float bo4[4] = {bgo.x, bgo.y, bgo.z, bgo.w};
        float bc4[4] = {bgc.x, bgc.y, bgc.z, bgc.w};
        float wo[4] = {wo4.x, wo4.y, wo4.z, wo4.w};
        float cn[4], hn[4];
        float part = 0.f;
#pragma unroll
        for (int r = 0; r < 4; ++r) {
            float fg = sigm(acc[0][fn][r] + bf4[r]);
            float ig = sigm(acc[1][fn][r] + bi4[r]);
            float og = sigm(acc[2][fn][r] + bo4[r]);
            float gg = sigm(acc[3][fn][r] + bc4[r]);
            cn[r] = fg * co[r] + ig * gg;
            hn[r] = og * sigm(cn[r]);
            part = fmaf(cn[r], wo[r], part);
        }
        float4 cnv; cnv.x = cn[0]; cnv.y = cn[1]; cnv.z = cn[2]; cnv.w = cn[3];
        *(float4*)&c[p * 32 + o0] = cnv;
        unsigned short hh[4], hl[4];
#pragma unroll
        for (int r = 0; r < 4; ++r) {
            hh[r] = f2bf(hn[r]);
            hl[r] = f2bf(hn[r] - bf2f(hh[r]));
        }
        uint2 ph, pl;
        ph.x = (unsigned)hh[0] | ((unsigned)hh[1] << 16);
        ph.y = (unsigned)hh[2] | ((unsigned)hh[3] << 16);
        pl.x = (unsigned)hl[0] | ((unsigned)hl[1] << 16);
        pl.y = (unsigned)hl[2] | ((unsigned)hl[3] << 16);
        *(uint2*)&h0[p * 32 + o0] = ph;
        *(uint2*)&h1g[p * 32 + o0] = pl;
        part += __shfl_xor(part, 16, 64);
        part += __shfl_xor(part, 32, 64);
        if (quad == 0) red[px * 2 + (wm >> 6)] = part;
    }
    __syncthreads();
    if (tid < 128) {
        float v = red[tid * 2] + red[tid * 2 + 1] + bout[0];
        v = fminf(fmaxf(v, -15.f), 15.f);
        float e = __expf(2.f * v);
        x[pbase + tid] += (e - 1.f) / (e + 1.f);
    }
}

// ---------------------------------------------------------------------------
extern "C" void kernel_launch(void* const* d_in, const int* in_sizes, int n_in,
                              void* d_out, int out_size, void* d_ws, size_t ws_size,
                              hipStream_t stream)
{
    const float* x_in  = (const float*)d_in[0];
    const float* Lrow  = (const float*)d_in[1];
    const float* Lcol  = (const float*)d_in[2];
    const float* theta = (const float*)d_in[3];
    const float* bias  = (const float*)d_in[4];
    const float* Wf = (const float*)d_in[5];
    const float* Uf = (const float*)d_in[6];
    const float* bf = (const float*)d_in[7];
    const float* Wi = (const float*)d_in[8];
    const float* Ui = (const float*)d_in[9];
    const float* bi = (const float*)d_in[10];
    const float* Wo = (const float*)d_in[11];
    const float* Uo = (const float*)d_in[12];
    const float* bo = (const float*)d_in[13];
    const float* Wc = (const float*)d_in[14];
    const float* Uc = (const float*)d_in[15];
    const float* bc = (const float*)d_in[16];
    const float* Wout = (const float*)d_in[17];
    const float* bout = (const float*)d_in[18];
    (void)in_sizes; (void)n_in; (void)out_size;

    float* out = (float*)d_out;   // working x buffer

    // ---- workspace pool (245.4 MB) ----
    float* ws   = (float*)d_ws;
    float* Cbig = ws;                                // 14,745,600 f (59 MB)
    float* c    = ws + 14745600;                     // 18,874,368 f
    ushort_t* h0 = (ushort_t*)(c + 18874368);        // 18,874,368 sh
    ushort_t* h1 = h0 + 18874368;                    // 18,874,368 sh
    f16_t* S0 = (f16_t*)(h1 + 18874368);             // 2*STK (Tr | Tc)
    f16_t* S1 = S0 + 2 * STK;
    f16_t* XR0 = S1 + 2 * STK;                       // STK
    f16_t* XR1 = XR0 + STK;
    ushort_t* Wstack = (ushort_t*)(XR1 + STK);       // 8192 sh
    f16_t* xT0 = (f16_t*)Cbig;                       // per-iter alias
    f16_t* xT1 = xT0 + MXK;
    if (ws_size < (size_t)245383168) return;

    hipMemcpyAsync(out, x_in, (size_t)MXK * 4, hipMemcpyDeviceToDevice, stream);

    prep_gate_weights<<<32, 256, 0, stream>>>(Wf, Wi, Wo, Wc, Uf, Ui, Uo, Uc,
                                              Wstack);
    init_split<<<MXK / 256, 256, 0, stream>>>(Lrow, Lcol, S0, S1);
    // Cheb recursion, Tr+Tc batched: A = T1 (= L), dual stack via halfStride
    for (int k = 2; k <= 4; ++k) {
        gemm_bt_h2<<<144, 256, 0, stream>>>(
            S0 + MXK, S1 + MXK,
            S0 + (size_t)(k - 1) * MXK, S1 + (size_t)(k - 1) * MXK,
            S0 + (size_t)(k - 2) * MXK, S1 + (size_t)(k - 2) * MXK,
            nullptr,
            S0 + (size_t)k * MXK, S1 + (size_t)k * MXK,
            DIM, DIM, 2, 12, STK);
    }

    for (int it = 0; it < 3; ++it) {
        transpose_cvt2<<<dim3(24, 24), 256, 0, stream>>>(out, xT0, xT1);
        // stage1: XRv = TrV @ x  (M=3840, N=768, K=768), f16x2s out
        gemm_bt_h2<<<360, 256, 0, stream>>>(
            S0, S1, xT0, xT1,
            nullptr, nullptr,
            nullptr, XR0, XR1, DIM, DIM, 1, 12, 0);
        // stage2: C_big = XRv @ TcV^T  (M=3840, N=3840, K=768), fp32 out
        gemm_bt_h2<<<1800, 256, 0, stream>>>(
            XR0, XR1, S0 + STK, S1 + STK,
            nullptr, nullptr,
            Cbig, nullptr, nullptr, DIM, 3840, 0, 60, 0);
        // gates: theta contraction + MFMA + LSTM + x += tanh(c.Wout+b)
        gate_theta_mfma<<<4608, 256, 0, stream>>>(
            Cbig, theta, bias, Wstack,
            bf, bi, bo, bc, Wout, bout, h0, h1, c, out, it == 0 ? 1 : 0);
    }
}

// Round 8
// 764.518 us; speedup vs baseline: 6.9800x; 1.2205x over previous
//
#include <hip/hip_runtime.h>
#include <hip/hip_bf16.h>
#include <stdint.h>

// ---------------------------------------------------------------------------
// MGCNN on MI355X — f16x2s MFMA conv + all-f16 MFMA gate kernel.
//
// f16x2s format (conv path): a = a1 + a2*2^-11, residual pre-scaled x2048.
// Conv GEMMs keep 3 products (acc1 = a1b1; acc2 = a1b2 + a2b1).
//
// R8 changes:
//  - stage2 emits Cbf as f16 single (29.5 MB); j=0 panel is a pack-copy of
//    XR (T_0 = I); transpose kernel writes x-split straight into XR rows
//    0..767 so stage1 only computes i=1..4.
//  - gate kernel: theta contraction as MFMA (A = Cb frags loaded directly
//    from global with k>=25 clamped; B = theta-stack f16), xc/h/W all f16
//    single (2^-11 < old bf16 2^-8), h global f16 single.
// ---------------------------------------------------------------------------

#define DIM 768
#define MXK 589824        // 768*768
#define STK 2949120       // 5*768*768
#define RSCALE 2048.0f
#define RINV   (1.0f / 2048.0f)

typedef _Float16 f16x8 __attribute__((ext_vector_type(8)));
typedef float f32x4 __attribute__((ext_vector_type(4)));
typedef unsigned short ushort_t;
typedef _Float16 f16_t;

__device__ __forceinline__ float sigm(float v) {
    return 1.0f / (1.0f + __expf(-v));
}
__device__ __forceinline__ void split2h(float f, f16_t& h1, f16_t& h2) {
    h1 = (f16_t)f;
    float r = f - (float)h1;
    h2 = (f16_t)(r * RSCALE);
}

// async 16B global->LDS (LDS dest = wave-uniform base + lane*16)
__device__ __forceinline__ void gl_lds16(const f16_t* g, f16_t* l) {
    auto gp = reinterpret_cast<const __attribute__((address_space(1))) uint32_t*>(
        reinterpret_cast<uintptr_t>(g));
    auto lp = reinterpret_cast<__attribute__((address_space(3))) uint32_t*>(
        reinterpret_cast<uintptr_t>(l));
    __builtin_amdgcn_global_load_lds(gp, lp, 16, 0, 0);
}

// ---------------------------------------------------------------------------
// init: T0 = I, T1 = L  ->  f16x2s, Tr stack then Tc stack per level
// ---------------------------------------------------------------------------
__global__ __launch_bounds__(256) void init_split(
    const float* __restrict__ Lrow, const float* __restrict__ Lcol,
    f16_t* __restrict__ S0, f16_t* __restrict__ S1)
{
    int idx = blockIdx.x * 256 + threadIdx.x;
    int p = idx / DIM, m = idx % DIM;
    f16_t eye = (p == m) ? (f16_t)1.0f : (f16_t)0.0f;
    S0[idx] = eye; S1[idx] = (f16_t)0.0f;
    S0[STK + idx] = eye; S1[STK + idx] = (f16_t)0.0f;
    f16_t h1, h2;
    split2h(Lrow[idx], h1, h2);
    S0[MXK + idx] = h1; S1[MXK + idx] = h2;
    split2h(Lcol[idx], h1, h2);
    S0[STK + MXK + idx] = h1; S1[STK + MXK + idx] = h2;
}

// ---------------------------------------------------------------------------
// prep: Wstack f16 [128 R][64 k] (R: o-half<<6 | gate<<4 | o&15) and
// thstack f16 [32 o][32 k=ij] (k>=25 -> 0)
// ---------------------------------------------------------------------------
__global__ __launch_bounds__(256) void prep_gate(
    const float* __restrict__ Wf, const float* __restrict__ Wi,
    const float* __restrict__ Wo, const float* __restrict__ Wc,
    const float* __restrict__ Uf, const float* __restrict__ Ui,
    const float* __restrict__ Uo, const float* __restrict__ Uc,
    const float* __restrict__ theta,
    f16_t* __restrict__ Wstack, f16_t* __restrict__ thstack)
{
    int idx = blockIdx.x * 256 + threadIdx.x;
    if (idx < 8192) {
        int R = idx >> 6, k = idx & 63;
        int g = (R >> 4) & 3, o = (R >> 6) * 16 + (R & 15);
        const float* Wg[4] = {Wf, Wi, Wo, Wc};
        const float* Ug[4] = {Uf, Ui, Uo, Uc};
        float v = (k < 32) ? Wg[g][k * 32 + o] : Ug[g][(k - 32) * 32 + o];
        Wstack[idx] = (f16_t)v;
    } else if (idx < 9216) {
        int t = idx - 8192;
        int o = t >> 5, k = t & 31;
        thstack[o * 32 + k] = (k < 25) ? (f16_t)theta[k * 32 + o] : (f16_t)0.0f;
    }
}

// ---------------------------------------------------------------------------
// transpose 768x768 + f16x2s split: xT[q][p] = x[p][q]; ALSO straight split
// of x into XR rows 0..767 (T_0 = I => XRv[(0,m)][q] = x[m][q]).
// ---------------------------------------------------------------------------
__global__ __launch_bounds__(256) void transpose_cvt2x(
    const float* __restrict__ in, f16_t* __restrict__ o1,
    f16_t* __restrict__ o2, f16_t* __restrict__ xr0,
    f16_t* __restrict__ xr1)
{
    __shared__ float t[32][33];
    int x = threadIdx.x & 31, y = threadIdx.x >> 5;
    int bx = blockIdx.x * 32, by = blockIdx.y * 32;
#pragma unroll
    for (int r = 0; r < 4; ++r) {
        size_t oi = (size_t)(by + y + 8 * r) * DIM + bx + x;
        float v = in[oi];
        t[y + 8 * r][x] = v;
        f16_t h1, h2;
        split2h(v, h1, h2);
        xr0[oi] = h1; xr1[oi] = h2;           // straight split (i = 0 panel)
    }
    __syncthreads();
#pragma unroll
    for (int r = 0; r < 4; ++r) {
        float v = t[x][y + 8 * r];
        f16_t h1, h2;
        split2h(v, h1, h2);
        size_t o = (size_t)(bx + y + 8 * r) * DIM + by + x;
        o1[o] = h1; o2[o] = h2;
    }
}

// ---------------------------------------------------------------------------
// pack_j0: Cbf[row][col<768] = f16(XR0 + XR1*2^-11)   (T_0 = I on the Tc side)
// ---------------------------------------------------------------------------
__global__ __launch_bounds__(256) void pack_j0(
    const f16_t* __restrict__ XR0, const f16_t* __restrict__ XR1,
    f16_t* __restrict__ Cbf)
{
    int idx = blockIdx.x * 256 + threadIdx.x;   // * 8 elems, 2,949,120 total
    int t = idx * 8;
    int row = t / DIM, col = t % DIM;
    const f16_t* a = XR0 + t;
    const f16_t* b = XR1 + t;
    f16_t o[8];
#pragma unroll
    for (int k = 0; k < 8; ++k)
        o[k] = (f16_t)((float)a[k] + (float)b[k] * RINV);
    *(uint4*)&Cbf[(size_t)row * 3840 + col] = *(const uint4*)o;
}

// ---------------------------------------------------------------------------
// f16x2s MFMA GEMM engine (B-transposed, k-contig), 128x64 tile, BK=32.
// 4 waves, wave tile 64x32 (dual acc = 64 VGPRs). XOR-swizzled LDS.
// mode 1: f16x2s out D1/D2; mode 2: cheb (v = 2*acc - P), dual stack via
// halfStride (by>=6); mode 3: f16 single out -> D1 (ldc, +coloff), supertile.
// ---------------------------------------------------------------------------
__global__ __launch_bounds__(256) void gemm_bt_h2(
    const f16_t* __restrict__ A1, const f16_t* __restrict__ A2,
    const f16_t* __restrict__ B1, const f16_t* __restrict__ B2,
    const f16_t* __restrict__ P1, const f16_t* __restrict__ P2,
    f16_t* __restrict__ D1, f16_t* __restrict__ D2,
    int K, int ldc, int mode, int nbx, int halfStride, int coloff)
{
    __shared__ __align__(16) f16_t sA[2][128 * 32];
    __shared__ __align__(16) f16_t sB[2][64 * 32];

    const int tid = threadIdx.x;

    int bx, by;
    size_t hoff = 0;
    if (mode == 3) {
        // supertile: 8 rows x nbx cols share A/B panels -> L2 reuse
        int g = blockIdx.x;
        int sup = g / (8 * nbx);
        int rows0 = sup * 8;
        int H = 30 - rows0; if (H > 8) H = 8;
        int local = g - rows0 * nbx;
        by = rows0 + local % H;
        bx = local / H;
    } else {
        bx = blockIdx.x % nbx;
        by = blockIdx.x / nbx;
        if (mode == 2 && by >= 6) { by -= 6; hoff = (size_t)halfStride; }
    }
    const int m0 = by * 128, n0 = bx * 64;

    const int lane = tid & 63, w4 = tid >> 6;
    const int wm = (w4 & 1) * 64, wn = (w4 >> 1) * 32;
    const int lm = lane & 15, quad = lane >> 4;
    const int psw = (quad ^ ((lm >> 1) & 3)) * 8;

    const int sA0i = (w4 * 2) * 64 + lane;
    const int sA1i = (w4 * 2 + 1) * 64 + lane;
    const int sB0i = w4 * 64 + lane;
    const int rA0 = sA0i >> 2, cA0 = (lane & 3) ^ ((rA0 >> 1) & 3);
    const int rA1 = sA1i >> 2, cA1 = (lane & 3) ^ ((rA1 >> 1) & 3);
    const int rB0 = sB0i >> 2, cB0 = (lane & 3) ^ ((rB0 >> 1) & 3);
    const int offA0 = rA0 * K + cA0 * 8;
    const int offA1 = rA1 * K + cA1 * 8;
    const int offB0 = rB0 * K + cB0 * 8;

    const f16_t* Ag0 = A1 + hoff + (size_t)m0 * K;
    const f16_t* Ag1 = A2 + hoff + (size_t)m0 * K;
    const f16_t* Bg0 = B1 + hoff + (size_t)n0 * K;
    const f16_t* Bg1 = B2 + hoff + (size_t)n0 * K;
    f16_t* dA00 = &sA[0][(w4 * 2) * 512];
    f16_t* dA01 = &sA[0][(w4 * 2 + 1) * 512];
    f16_t* dA10 = &sA[1][(w4 * 2) * 512];
    f16_t* dA11 = &sA[1][(w4 * 2 + 1) * 512];
    f16_t* dB0  = &sB[0][w4 * 512];
    f16_t* dB1  = &sB[1][w4 * 512];

    f32x4 acc1[4][2] = {};
    f32x4 acc2[4][2] = {};

    for (int kb = 0; kb < K; kb += 32) {
        gl_lds16(Ag0 + offA0 + kb, dA00);
        gl_lds16(Ag0 + offA1 + kb, dA01);
        gl_lds16(Ag1 + offA0 + kb, dA10);
        gl_lds16(Ag1 + offA1 + kb, dA11);
        gl_lds16(Bg0 + offB0 + kb, dB0);
        gl_lds16(Bg1 + offB0 + kb, dB1);
        __syncthreads();

        f16x8 bfr[2][2];
#pragma unroll
        for (int l = 0; l < 2; ++l)
#pragma unroll
            for (int fn = 0; fn < 2; ++fn)
                bfr[l][fn] = *(const f16x8*)&sB[l][(wn + fn * 16 + lm) * 32 + psw];
#pragma unroll
        for (int fm = 0; fm < 4; ++fm) {
            const int ar = (wm + fm * 16 + lm) * 32 + psw;
            f16x8 a1 = *(const f16x8*)&sA[0][ar];
            f16x8 a2 = *(const f16x8*)&sA[1][ar];
#pragma unroll
            for (int fn = 0; fn < 2; ++fn) {
                acc2[fm][fn] = __builtin_amdgcn_mfma_f32_16x16x32_f16(
                    a2, bfr[0][fn], acc2[fm][fn], 0, 0, 0);
                acc2[fm][fn] = __builtin_amdgcn_mfma_f32_16x16x32_f16(
                    a1, bfr[1][fn], acc2[fm][fn], 0, 0, 0);
                acc1[fm][fn] = __builtin_amdgcn_mfma_f32_16x16x32_f16(
                    a1, bfr[0][fn], acc1[fm][fn], 0, 0, 0);
            }
        }
        __syncthreads();
    }

    // epilogue: C/D layout col=lane&15, row=quad*4+reg  [verified m89/m91]
#pragma unroll
    for (int fm = 0; fm < 4; ++fm)
#pragma unroll
        for (int fn = 0; fn < 2; ++fn) {
            int col = n0 + wn + fn * 16 + lm;
#pragma unroll
            for (int r = 0; r < 4; ++r) {
                int row = m0 + wm + fm * 16 + quad * 4 + r;
                float val = acc1[fm][fn][r] + acc2[fm][fn][r] * RINV;
                if (mode == 3) {
                    D1[(size_t)row * ldc + coloff + col] = (f16_t)val;
                } else {
                    size_t o = (size_t)row * ldc + col;
                    if (mode == 2)
                        val = 2.0f * val -
                              ((float)P1[hoff + o] + (float)P2[hoff + o] * RINV);
                    f16_t h1, h2;
                    split2h(val, h1, h2);
                    D1[hoff + o] = h1; D2[hoff + o] = h2;
                }
            }
        }
}

// ---------------------------------------------------------------------------
// Gate kernel v2 (all f16). Block = 128 pixels (m = blk/6, n0 = (blk%6)*128).
//  1) theta-MFMA: A = Cbf frags direct from global (m=px, k=ij, k>=25
//     clamped to 24 so theta=0 kills them w/o NaN), B = thstack -> xc,
//     +bias, f16 -> sB[px][0..31]
//  2) h (f16 global) -> sB[px][32..63] (zeros if first)
//  3) gate MFMA: A = Wstack f16, B = sB; LSTM elementwise; c f32, h f16,
//     x += tanh(c . Wout + bout) via shuffle+LDS reduce
// ---------------------------------------------------------------------------
__global__ __launch_bounds__(256) void gate_theta_mfma(
    const f16_t* __restrict__ Cbf, const f16_t* __restrict__ thstack,
    const float* __restrict__ bias, const f16_t* __restrict__ Wstack,
    const float* __restrict__ bfv, const float* __restrict__ biv,
    const float* __restrict__ bov, const float* __restrict__ bcv,
    const float* __restrict__ Wout, const float* __restrict__ bout,
    f16_t* __restrict__ h, float* __restrict__ c, float* __restrict__ x,
    int first)
{
    __shared__ __align__(16) ushort_t sB[128 * 72];  // f16 bits [px][k]
    __shared__ float red[256];

    const int tid = threadIdx.x;
    const int lane = tid & 63, w4 = tid >> 6;
    const int wm = (w4 & 1) * 64, wn = (w4 >> 1) * 64;
    const int lm = lane & 15, quad = lane >> 4;
    const int m = blockIdx.x / 6;
    const int n0 = (blockIdx.x % 6) * 128;
    const int pbase = m * DIM + n0;

    // gate A-frags (weights f16) straight from global (L2-resident, 16 KB)
    f16x8 af[4][2];
#pragma unroll
    for (int fm = 0; fm < 4; ++fm)
#pragma unroll
        for (int kc = 0; kc < 2; ++kc)
            af[fm][kc] = *(const f16x8*)&Wstack[(wm + fm * 16 + lm) * 64 +
                                                kc * 32 + quad * 8];

    // theta B-frags (thstack [o][32k])
    f16x8 bth[2];
#pragma unroll
    for (int fn = 0; fn < 2; ++fn)
        bth[fn] = *(const f16x8*)&thstack[(fn * 16 + lm) * 32 + quad * 8];

    // h staging -> sB[px][32..63]  (thread: px = t>>1, 16-u16 half = t&1)
    {
        int px = tid >> 1, part = tid & 1;
        uint4 v0, v1;
        if (first) {
            v0.x = v0.y = v0.z = v0.w = 0u; v1 = v0;
        } else {
            const uint4* src = (const uint4*)&h[(size_t)(pbase + px) * 32 + part * 16];
            v0 = src[0]; v1 = src[1];
        }
        uint4* dst = (uint4*)&sB[px * 72 + 32 + part * 16];
        dst[0] = v0; dst[1] = v1;
    }

    // theta-MFMA: wave covers px [w4*32, w4*32+32)
    const int pw = w4 * 32;
    f32x4 tacc[2][2] = {};
    {
        int aoff[8];
#pragma unroll
        for (int j = 0; j < 8; ++j) {
            int k = quad * 8 + j;
            int ij = k > 24 ? 24 : k;
            int i5 = (ij * 205) >> 10;          // ij/5 for ij<32
            int j5 = ij - i5 * 5;
            aoff[j] = (i5 * DIM + m) * 3840 + j5 * DIM + n0 + pw + lm;
        }
        f16x8 a0, a1;
#pragma unroll
        for (int j = 0; j < 8; ++j) {
            a0[j] = Cbf[(size_t)aoff[j]];
            a1[j] = Cbf[(size_t)aoff[j] + 16];
        }
#pragma unroll
        for (int fn = 0; fn < 2; ++fn) {
            tacc[0][fn] = __builtin_amdgcn_mfma_f32_16x16x32_f16(
                a0, bth[fn], tacc[0][fn], 0, 0, 0);
            tacc[1][fn] = __builtin_amdgcn_mfma_f32_16x16x32_f16(
                a1, bth[fn], tacc[1][fn], 0, 0, 0);
        }
    }
    // xc = tacc + bias -> f16 -> sB[px][o]
    {
        float b0 = bias[lm], b1 = bias[16 + lm];
#pragma unroll
        for (int fm2 = 0; fm2 < 2; ++fm2)
#pragma unroll
            for (int fn = 0; fn < 2; ++fn) {
                float bb = fn ? b1 : b0;
#pragma unroll
                for (int r = 0; r < 4; ++r) {
                    float v = tacc[fm2][fn][r] + bb;
                    f16_t hv = (f16_t)v;
                    sB[(pw + fm2 * 16 + quad * 4 + r) * 72 + fn * 16 + lm] =
                        __builtin_bit_cast(ushort_t, hv);
                }
            }
    }
    __syncthreads();

    // gate MFMA: acc[g][fn] over K=64 (2 chunks), single f16 level
    f32x4 acc[4][4] = {};
#pragma unroll
    for (int kc = 0; kc < 2; ++kc) {
        f16x8 bfr[4];
#pragma unroll
        for (int fn = 0; fn < 4; ++fn)
            bfr[fn] = *(const f16x8*)&sB[(wn + fn * 16 + lm) * 72 +
                                         kc * 32 + quad * 8];
#pragma unroll
        for (int fm = 0; fm < 4; ++fm)
#pragma unroll
            for (int fn = 0; fn < 4; ++fn)
                acc[fm][fn] = __builtin_amdgcn_mfma_f32_16x16x32_f16(
                    af[fm][kc], bfr[fn], acc[fm][fn], 0, 0, 0);
    }

    // epilogue: lane holds gates g=fm for o = o0..o0+3, pixel = wn+fn*16+lm
    const int o0 = (wm >> 2) + quad * 4;
    const float4 bgf = *(const float4*)&bfv[o0];
    const float4 bgi = *(const float4*)&biv[o0];
    const float4 bgo = *(const float4*)&bov[o0];
    const float4 bgc = *(const float4*)&bcv[o0];
    const float4 wo4 = *(const float4*)&Wout[o0];

#pragma unroll
    for (int fn = 0; fn < 4; ++fn) {
        int px = wn + fn * 16 + lm;
        size_t p = (size_t)(pbase + px);
        float4 cold;
        if (first) { cold.x = cold.y = cold.z = cold.w = 0.f; }
        else cold = *(const float4*)&c[p * 32 + o0];
        float co[4] = {cold.x, cold.y, cold.z, cold.w};
        float bf4[4] = {bgf.x, bgf.y, bgf.z, bgf.w};
        float bi4[4] = {bgi.x, bgi.y, bgi.z, bgi.w};
        float bo4[4] = {bgo.x, bgo.y, bgo.z, bgo.w};
        float bc4[4] = {bgc.x, bgc.y, bgc.z, bgc.w};
        float wo[4] = {wo4.x, wo4.y, wo4.z, wo4.w};
        float cn[4];
        f16_t hn[4];
        float part = 0.f;
#pragma unroll
        for (int r = 0; r < 4; ++r) {
            float fg = sigm(acc[0][fn][r] + bf4[r]);
            float ig = sigm(acc[1][fn][r] + bi4[r]);
            float og = sigm(acc[2][fn][r] + bo4[r]);
            float gg = sigm(acc[3][fn][r] + bc4[r]);
            cn[r] = fg * co[r] + ig * gg;
            hn[r] = (f16_t)(og * sigm(cn[r]));
            part = fmaf(cn[r], wo[r], part);
        }
        float4 cnv; cnv.x = cn[0]; cnv.y = cn[1]; cnv.z = cn[2]; cnv.w = cn[3];
        *(float4*)&c[p * 32 + o0] = cnv;
        *(uint2*)&h[p * 32 + o0] = *(const uint2*)hn;
        part += __shfl_xor(part, 16, 64);
        part += __shfl_xor(part, 32, 64);
        if (quad == 0) red[px * 2 + (wm >> 6)] = part;
    }
    __syncthreads();
    if (tid < 128) {
        float v = red[tid * 2] + red[tid * 2 + 1] + bout[0];
        v = fminf(fmaxf(v, -15.f), 15.f);
        float e = __expf(2.f * v);
        x[pbase + tid] += (e - 1.f) / (e + 1.f);
    }
}

// ---------------------------------------------------------------------------
extern "C" void kernel_launch(void* const* d_in, const int* in_sizes, int n_in,
                              void* d_out, int out_size, void* d_ws, size_t ws_size,
                              hipStream_t stream)
{
    const float* x_in  = (const float*)d_in[0];
    const float* Lrow  = (const float*)d_in[1];
    const float* Lcol  = (const float*)d_in[2];
    const float* theta = (const float*)d_in[3];
    const float* bias  = (const float*)d_in[4];
    const float* Wf = (const float*)d_in[5];
    const float* Uf = (const float*)d_in[6];
    const float* bf = (const float*)d_in[7];
    const float* Wi = (const float*)d_in[8];
    const float* Ui = (const float*)d_in[9];
    const float* bi = (const float*)d_in[10];
    const float* Wo = (const float*)d_in[11];
    const float* Uo = (const float*)d_in[12];
    const float* bo = (const float*)d_in[13];
    const float* Wc = (const float*)d_in[14];
    const float* Uc = (const float*)d_in[15];
    const float* bc = (const float*)d_in[16];
    const float* Wout = (const float*)d_in[17];
    const float* bout = (const float*)d_in[18];
    (void)in_sizes; (void)n_in; (void)out_size;

    float* out = (float*)d_out;   // working x buffer

    // ---- workspace pool (178.1 MB) ----
    float* ws   = (float*)d_ws;
    float* c    = ws;                                // 18,874,368 f
    f16_t* Cbf  = (f16_t*)(c + 18874368);            // 14,745,600 f16
    f16_t* h    = Cbf + 14745600;                    // 18,874,368 f16
    f16_t* S0   = h + 18874368;                      // 2*STK (Tr | Tc)
    f16_t* S1   = S0 + 2 * STK;
    f16_t* XR0  = S1 + 2 * STK;                      // STK
    f16_t* XR1  = XR0 + STK;
    f16_t* Wstack  = XR1 + STK;                      // 8192
    f16_t* thstack = Wstack + 8192;                  // 1024
    f16_t* xT0  = Cbf;                               // per-iter alias (dead
    f16_t* xT1  = xT0 + MXK;                         //  before Cbf writes)
    if (ws_size < (size_t)178145280) return;

    hipMemcpyAsync(out, x_in, (size_t)MXK * 4, hipMemcpyDeviceToDevice, stream);

    prep_gate<<<36, 256, 0, stream>>>(Wf, Wi, Wo, Wc, Uf, Ui, Uo, Uc, theta,
                                      Wstack, thstack);
    init_split<<<MXK / 256, 256, 0, stream>>>(Lrow, Lcol, S0, S1);
    // Cheb recursion, Tr+Tc batched: A = T1 (= L), dual stack via halfStride
    for (int k = 2; k <= 4; ++k) {
        gemm_bt_h2<<<144, 256, 0, stream>>>(
            S0 + MXK, S1 + MXK,
            S0 + (size_t)(k - 1) * MXK, S1 + (size_t)(k - 1) * MXK,
            S0 + (size_t)(k - 2) * MXK, S1 + (size_t)(k - 2) * MXK,
            S0 + (size_t)k * MXK, S1 + (size_t)k * MXK,
            DIM, DIM, 2, 12, STK, 0);
    }

    for (int it = 0; it < 3; ++it) {
        // xT split + straight x split into XR rows 0..767 (T_0 = I)
        transpose_cvt2x<<<dim3(24, 24), 256, 0, stream>>>(out, xT0, xT1,
                                                          XR0, XR1);
        // stage1: XR rows 768..3839 = T_{1..4} @ x  (M=3072, K=768)
        gemm_bt_h2<<<288, 256, 0, stream>>>(
            S0 + MXK, S1 + MXK, xT0, xT1,
            nullptr, nullptr,
            XR0 + MXK, XR1 + MXK, DIM, DIM, 1, 12, 0, 0);
        // Cbf cols 0..767 = XR (T_0 = I on Tc side)
        pack_j0<<<1440, 256, 0, stream>>>(XR0, XR1, Cbf);
        // stage2: Cbf cols 768.. = XR @ Tc_{1..4}^T (M=3840, N=3072, K=768)
        gemm_bt_h2<<<1440, 256, 0, stream>>>(
            XR0, XR1, S0 + STK + MXK, S1 + STK + MXK,
            nullptr, nullptr,
            Cbf, nullptr, DIM, 3840, 3, 48, 0, DIM);
        // gates: theta-MFMA + gate-MFMA + LSTM + x += tanh(c.Wout+b)
        gate_theta_mfma<<<4608, 256, 0, stream>>>(
            Cbf, thstack, bias, Wstack,
            bf, bi, bo, bc, Wout, bout, h, c, out, it == 0 ? 1 : 0);
    }
}